// Round 1
// baseline (796.099 us; speedup 1.0000x reference)
//
#include <hip/hip_runtime.h>
#include <math.h>

#define NN 50000
#define NE 800000
#define NG 64

typedef __attribute__((ext_vector_type(8))) __bf16 bf16x8;
typedef __attribute__((ext_vector_type(8))) short short8;
typedef __attribute__((ext_vector_type(4))) float f32x4;

__device__ inline unsigned short f2bf(float f) {
    unsigned int u = __float_as_uint(f);
    u += 0x7fffu + ((u >> 16) & 1u);   // round-to-nearest-even
    return (unsigned short)(u >> 16);
}

// ---------------- CSR build ----------------
__global__ void count_k(const int* __restrict__ dst, int* __restrict__ cnt) {
    int e = blockIdx.x * 256 + threadIdx.x;
    if (e < NE) atomicAdd(&cnt[dst[e]], 1);
}

__global__ __launch_bounds__(1024) void scan_k(const int* __restrict__ cnt,
                                               int* __restrict__ rowptr) {
    __shared__ int sums[1024];
    const int CH = 49;                  // 1024*49 = 50176 >= 50000
    int t = threadIdx.x;
    int base = t * CH;
    int s = 0;
    for (int i = 0; i < CH; ++i) { int idx = base + i; if (idx < NN) s += cnt[idx]; }
    sums[t] = s;
    __syncthreads();
    for (int off = 1; off < 1024; off <<= 1) {
        int v = (t >= off) ? sums[t - off] : 0;
        __syncthreads();
        sums[t] += v;
        __syncthreads();
    }
    int prefix = (t == 0) ? 0 : sums[t - 1];   // exclusive
    for (int i = 0; i < CH; ++i) {
        int idx = base + i;
        if (idx < NN) { rowptr[idx] = prefix; prefix += cnt[idx]; }
    }
    if (t == 1023) rowptr[NN] = prefix;        // == total (=NE)
}

__global__ void copy_k(const int* __restrict__ a, int* __restrict__ b) {
    int i = blockIdx.x * 256 + threadIdx.x;
    if (i < NN) b[i] = a[i];
}

__global__ void fill_k(const int* __restrict__ src, const int* __restrict__ dst,
                       int* __restrict__ cursor, int* __restrict__ colsrc) {
    int e = blockIdx.x * 256 + threadIdx.x;
    if (e < NE) {
        int d = dst[e];
        int pos = atomicAdd(&cursor[d], 1);
        colsrc[pos] = src[e];
    }
}

// ---------------- edge aggregation (CSR, one wave per node, d=128) ----------------
__global__ __launch_bounds__(256) void agg_k(const float* __restrict__ feat,
                                             const int* __restrict__ rowptr,
                                             const int* __restrict__ colsrc,
                                             float* __restrict__ out) {
    int node = __builtin_amdgcn_readfirstlane((int)(blockIdx.x * 4 + (threadIdx.x >> 6)));
    int lane = threadIdx.x & 63;
    int beg = rowptr[node], end = rowptr[node + 1];
    float2 acc = make_float2(0.f, 0.f);
    for (int e = beg; e < end; ++e) {
        int s = colsrc[e];
        float2 v = *(const float2*)&feat[(size_t)s * 128 + lane * 2];
        acc.x += v.x; acc.y += v.y;
    }
    *(float2*)&out[(size_t)node * 128 + lane * 2] = acc;
}

// ---------------- fused GEMM: C = act(A1@W1 [+ A2@W2] [+ bias]) via bf16 MFMA --------
// A: [M,KA] fp32 row-major (concat trick: K' = 2*KA when TWO).  W: [K',N] fp32 row-major.
template <int KA, int N, bool TWO, bool BIAS, bool ELU>
__global__ __launch_bounds__(256) void gemm_k(const float* __restrict__ A1,
                                              const float* __restrict__ A2,
                                              const float* __restrict__ W1,
                                              const float* __restrict__ W2,
                                              const float* __restrict__ bias,
                                              float* __restrict__ Cout) {
    constexpr int KTOT = TWO ? 2 * KA : KA;
    __shared__ __attribute__((aligned(16))) unsigned short As[64][40];  // [m][k] bf16, +8 pad
    __shared__ __attribute__((aligned(16))) unsigned short Bs[64][40];  // [n][k] bf16 (W^T)
    const int t = threadIdx.x;
    const int m0 = blockIdx.x * 64;
    const int n0 = blockIdx.y * 64;
    const int wv = t >> 6, lane = t & 63, qd = lane >> 4, l16 = lane & 15;
    f32x4 acc[4] = {};

    const int arow = t >> 2;           // 0..63
    const int akk  = (t & 3) << 3;     // 0,8,16,24
    const int wkl  = t >> 3;           // 0..31
    const int wng  = (t & 7) << 3;     // 0..56
    const int gm = m0 + arow;

    for (int k0 = 0; k0 < KTOT; k0 += 32) {
        {   // stage A tile 64x32 (fp32 -> bf16)
            int kabs = k0 + akk;
            const float* src = (TWO && kabs >= KA) ? (A2 + (size_t)gm * KA + (kabs - KA))
                                                   : (A1 + (size_t)gm * KA + kabs);
            float4 v0 = make_float4(0.f, 0.f, 0.f, 0.f), v1 = v0;
            if (gm < NN) { v0 = *(const float4*)src; v1 = *(const float4*)(src + 4); }
            short8 sv;
            sv[0] = (short)f2bf(v0.x); sv[1] = (short)f2bf(v0.y);
            sv[2] = (short)f2bf(v0.z); sv[3] = (short)f2bf(v0.w);
            sv[4] = (short)f2bf(v1.x); sv[5] = (short)f2bf(v1.y);
            sv[6] = (short)f2bf(v1.z); sv[7] = (short)f2bf(v1.w);
            *(short8*)&As[arow][akk] = sv;
        }
        {   // stage W tile 32x64, transposed into Bs[n][k]
            int kabs = k0 + wkl;
            const float* src = (TWO && kabs >= KA) ? (W2 + (size_t)(kabs - KA) * N + n0 + wng)
                                                   : (W1 + (size_t)kabs * N + n0 + wng);
            float4 v0 = *(const float4*)src;
            float4 v1 = *(const float4*)(src + 4);
            Bs[wng + 0][wkl] = f2bf(v0.x); Bs[wng + 1][wkl] = f2bf(v0.y);
            Bs[wng + 2][wkl] = f2bf(v0.z); Bs[wng + 3][wkl] = f2bf(v0.w);
            Bs[wng + 4][wkl] = f2bf(v1.x); Bs[wng + 5][wkl] = f2bf(v1.y);
            Bs[wng + 6][wkl] = f2bf(v1.z); Bs[wng + 7][wkl] = f2bf(v1.w);
        }
        __syncthreads();
        // wave wv computes rows [wv*16, wv*16+16) x all 64 cols; one K=32 MFMA step
        bf16x8 af = *(const bf16x8*)&As[wv * 16 + l16][qd * 8];
#pragma unroll
        for (int j = 0; j < 4; ++j) {
            bf16x8 bfv = *(const bf16x8*)&Bs[j * 16 + l16][qd * 8];
            acc[j] = __builtin_amdgcn_mfma_f32_16x16x32_bf16(af, bfv, acc[j], 0, 0, 0);
        }
        __syncthreads();
    }
#pragma unroll
    for (int j = 0; j < 4; ++j) {
#pragma unroll
        for (int r = 0; r < 4; ++r) {
            int mm = m0 + wv * 16 + qd * 4 + r;   // C/D: row = quad*4 + reg
            if (mm < NN) {
                int nn = n0 + j * 16 + l16;       // col = lane&15
                float v = acc[j][r];
                if (BIAS) v += bias[nn];
                if (ELU) v = v > 0.f ? v : (__expf(v) - 1.f);
                Cout[(size_t)mm * N + nn] = v;
            }
        }
    }
}

// ---------------- epilogue: elu(agg_y + r + b3) -> graph sums -> mean ----------------
__global__ void graphcnt_k(const int* __restrict__ batch, int* __restrict__ gcnt) {
    int n = blockIdx.x * 256 + threadIdx.x;
    if (n < NN) atomicAdd(&gcnt[batch[n]], 1);
}

__global__ __launch_bounds__(128) void finalize_k(const float* __restrict__ aggy,
                                                  const float* __restrict__ rr,
                                                  const float* __restrict__ b3,
                                                  const int* __restrict__ batch,
                                                  float* __restrict__ out) {
    int n = blockIdx.x, c = threadIdx.x;
    size_t idx = (size_t)n * 128 + c;
    float v = aggy[idx] + rr[idx] + b3[c];
    v = v > 0.f ? v : (__expf(v) - 1.f);
    unsafeAtomicAdd(&out[batch[n] * 128 + c], v);
}

__global__ void divide_k(const int* __restrict__ gcnt, float* __restrict__ out) {
    int i = blockIdx.x * 256 + threadIdx.x;
    if (i < NG * 128) {
        float c = (float)gcnt[i >> 7];
        out[i] /= fmaxf(c, 1.f);
    }
}

extern "C" void kernel_launch(void* const* d_in, const int* in_sizes, int n_in,
                              void* d_out, int out_size, void* d_ws, size_t ws_size,
                              hipStream_t stream) {
    const float* x       = (const float*)d_in[0];
    const int*   ei      = (const int*)d_in[1];
    const int*   batch   = (const int*)d_in[2];
    const float* w_rel1  = (const float*)d_in[3];
    const float* b_rel1  = (const float*)d_in[4];
    const float* w_root1 = (const float*)d_in[5];
    const float* w_rel2  = (const float*)d_in[6];
    const float* b_rel2  = (const float*)d_in[7];
    const float* w_root2 = (const float*)d_in[8];
    const float* w_rel3  = (const float*)d_in[9];
    const float* b_rel3  = (const float*)d_in[10];
    const float* w_root3 = (const float*)d_in[11];
    const int* esrc = ei;
    const int* edst = ei + NE;

    // workspace layout (fp32): A[NN*128] B[NN*128] C[NN*256], then ints
    float* A = (float*)d_ws;
    float* B = A + (size_t)NN * 128;
    float* C = B + (size_t)NN * 128;
    int* rowptr = (int*)(C + (size_t)NN * 256);
    int* cursor = rowptr + (NN + 1);
    int* colsrc = cursor + NN;
    int* gcnt   = colsrc + NE;
    float* outp = (float*)d_out;

    // --- CSR build (per launch; same work every call) ---
    hipMemsetAsync(cursor, 0, NN * sizeof(int), stream);
    count_k<<<(NE + 255) / 256, 256, 0, stream>>>(edst, cursor);
    scan_k<<<1, 1024, 0, stream>>>(cursor, rowptr);
    copy_k<<<(NN + 255) / 256, 256, 0, stream>>>(rowptr, cursor);
    fill_k<<<(NE + 255) / 256, 256, 0, stream>>>(esrc, edst, cursor, colsrc);

    dim3 g2(782, 2), g4(782, 4);

    // L1: h1 = elu([agg(x) | x] @ [w_rel1; w_root1] + b1)    -> B
    agg_k<<<NN / 4, 256, 0, stream>>>(x, rowptr, colsrc, A);
    gemm_k<128, 128, true, true, true><<<g2, 256, 0, stream>>>(A, x, w_rel1, w_root1, b_rel1, B);

    // L2: h2 = elu([agg(h1) | h1] @ [w_rel2; w_root2] + b2)  -> C
    agg_k<<<NN / 4, 256, 0, stream>>>(B, rowptr, colsrc, A);
    gemm_k<128, 256, true, true, true><<<g4, 256, 0, stream>>>(A, B, w_rel2, w_root2, b_rel2, C);

    // L3: y = h2@w_rel3 -> A ; r = h2@w_root3 -> B ; agg(y) -> C(front)
    gemm_k<256, 128, false, false, false><<<g2, 256, 0, stream>>>(C, nullptr, w_rel3, nullptr, nullptr, A);
    gemm_k<256, 128, false, false, false><<<g2, 256, 0, stream>>>(C, nullptr, w_root3, nullptr, nullptr, B);
    agg_k<<<NN / 4, 256, 0, stream>>>(A, rowptr, colsrc, C);

    // scatter_mean
    hipMemsetAsync(outp, 0, NG * 128 * sizeof(float), stream);
    hipMemsetAsync(gcnt, 0, NG * sizeof(int), stream);
    graphcnt_k<<<(NN + 255) / 256, 256, 0, stream>>>(batch, gcnt);
    finalize_k<<<NN, 128, 0, stream>>>(C, B, b_rel3, batch, outp);
    divide_k<<<(NG * 128 + 255) / 256, 256, 0, stream>>>(gcnt, outp);
}

// Round 2
// 637.851 us; speedup vs baseline: 1.2481x; 1.2481x over previous
//
#include <hip/hip_runtime.h>
#include <math.h>

#define NN 50000
#define NE 800000
#define NG 64

typedef __attribute__((ext_vector_type(8))) __bf16 bf16x8;
typedef __attribute__((ext_vector_type(8))) short short8;
typedef __attribute__((ext_vector_type(4))) float f32x4;

__device__ inline unsigned short f2bf(float f) {
    unsigned int u = __float_as_uint(f);
    u += 0x7fffu + ((u >> 16) & 1u);   // round-to-nearest-even
    return (unsigned short)(u >> 16);
}

// ---------------- CSR build ----------------
__global__ void count_k(const int* __restrict__ dst, int* __restrict__ cnt) {
    int e = blockIdx.x * 256 + threadIdx.x;
    if (e < NE) atomicAdd(&cnt[dst[e]], 1);
}

__global__ __launch_bounds__(1024) void scan_k(const int* __restrict__ cnt,
                                               int* __restrict__ rowptr) {
    __shared__ int sums[1024];
    const int CH = 49;                  // 1024*49 = 50176 >= 50000
    int t = threadIdx.x;
    int base = t * CH;
    int s = 0;
    for (int i = 0; i < CH; ++i) { int idx = base + i; if (idx < NN) s += cnt[idx]; }
    sums[t] = s;
    __syncthreads();
    for (int off = 1; off < 1024; off <<= 1) {
        int v = (t >= off) ? sums[t - off] : 0;
        __syncthreads();
        sums[t] += v;
        __syncthreads();
    }
    int prefix = (t == 0) ? 0 : sums[t - 1];   // exclusive
    for (int i = 0; i < CH; ++i) {
        int idx = base + i;
        if (idx < NN) { rowptr[idx] = prefix; prefix += cnt[idx]; }
    }
    if (t == 1023) rowptr[NN] = prefix;        // == total (=NE)
}

__global__ void copy_k(const int* __restrict__ a, int* __restrict__ b) {
    int i = blockIdx.x * 256 + threadIdx.x;
    if (i < NN) b[i] = a[i];
}

__global__ void fill_k(const int* __restrict__ src, const int* __restrict__ dst,
                       int* __restrict__ cursor, int* __restrict__ colsrc) {
    int e = blockIdx.x * 256 + threadIdx.x;
    if (e < NE) {
        int d = dst[e];
        int pos = atomicAdd(&cursor[d], 1);
        colsrc[pos] = src[e];
    }
}

// ---------------- edge aggregation (CSR, one wave per node, d=128) ----------------
__global__ __launch_bounds__(256) void agg_k(const float* __restrict__ feat,
                                             const int* __restrict__ rowptr,
                                             const int* __restrict__ colsrc,
                                             float* __restrict__ out) {
    int node = __builtin_amdgcn_readfirstlane((int)(blockIdx.x * 4 + (threadIdx.x >> 6)));
    int lane = threadIdx.x & 63;
    int beg = rowptr[node], end = rowptr[node + 1];
    float2 acc = make_float2(0.f, 0.f);
    for (int e = beg; e < end; ++e) {
        int s = colsrc[e];
        float2 v = *(const float2*)&feat[(size_t)s * 128 + lane * 2];
        acc.x += v.x; acc.y += v.y;
    }
    *(float2*)&out[(size_t)node * 128 + lane * 2] = acc;
}

// ---------------- fused GEMM: C = act(A1@W1 [+ A2@W2] [+ bias]) via bf16 MFMA --------
// A: [M,KA] fp32 row-major (concat trick: K' = 2*KA when TWO).  W: [K',N] fp32 row-major.
template <int KA, int N, bool TWO, bool BIAS, bool ELU>
__global__ __launch_bounds__(256) void gemm_k(const float* __restrict__ A1,
                                              const float* __restrict__ A2,
                                              const float* __restrict__ W1,
                                              const float* __restrict__ W2,
                                              const float* __restrict__ bias,
                                              float* __restrict__ Cout) {
    constexpr int KTOT = TWO ? 2 * KA : KA;
    __shared__ __attribute__((aligned(16))) unsigned short As[64][40];  // [m][k] bf16, +8 pad
    __shared__ __attribute__((aligned(16))) unsigned short Bs[64][40];  // [n][k] bf16 (W^T)
    const int t = threadIdx.x;
    const int m0 = blockIdx.x * 64;
    const int n0 = blockIdx.y * 64;
    const int wv = t >> 6, lane = t & 63, qd = lane >> 4, l16 = lane & 15;
    f32x4 acc[4] = {};

    const int arow = t >> 2;           // 0..63
    const int akk  = (t & 3) << 3;     // 0,8,16,24
    const int wkl  = t >> 3;           // 0..31
    const int wng  = (t & 7) << 3;     // 0..56
    const int gm = m0 + arow;

    for (int k0 = 0; k0 < KTOT; k0 += 32) {
        {   // stage A tile 64x32 (fp32 -> bf16)
            int kabs = k0 + akk;
            const float* src = (TWO && kabs >= KA) ? (A2 + (size_t)gm * KA + (kabs - KA))
                                                   : (A1 + (size_t)gm * KA + kabs);
            float4 v0 = make_float4(0.f, 0.f, 0.f, 0.f), v1 = v0;
            if (gm < NN) { v0 = *(const float4*)src; v1 = *(const float4*)(src + 4); }
            short8 sv;
            sv[0] = (short)f2bf(v0.x); sv[1] = (short)f2bf(v0.y);
            sv[2] = (short)f2bf(v0.z); sv[3] = (short)f2bf(v0.w);
            sv[4] = (short)f2bf(v1.x); sv[5] = (short)f2bf(v1.y);
            sv[6] = (short)f2bf(v1.z); sv[7] = (short)f2bf(v1.w);
            *(short8*)&As[arow][akk] = sv;
        }
        {   // stage W tile 32x64, transposed into Bs[n][k]
            int kabs = k0 + wkl;
            const float* src = (TWO && kabs >= KA) ? (W2 + (size_t)(kabs - KA) * N + n0 + wng)
                                                   : (W1 + (size_t)kabs * N + n0 + wng);
            float4 v0 = *(const float4*)src;
            float4 v1 = *(const float4*)(src + 4);
            Bs[wng + 0][wkl] = f2bf(v0.x); Bs[wng + 1][wkl] = f2bf(v0.y);
            Bs[wng + 2][wkl] = f2bf(v0.z); Bs[wng + 3][wkl] = f2bf(v0.w);
            Bs[wng + 4][wkl] = f2bf(v1.x); Bs[wng + 5][wkl] = f2bf(v1.y);
            Bs[wng + 6][wkl] = f2bf(v1.z); Bs[wng + 7][wkl] = f2bf(v1.w);
        }
        __syncthreads();
        // wave wv computes rows [wv*16, wv*16+16) x all 64 cols; one K=32 MFMA step
        bf16x8 af = *(const bf16x8*)&As[wv * 16 + l16][qd * 8];
#pragma unroll
        for (int j = 0; j < 4; ++j) {
            bf16x8 bfv = *(const bf16x8*)&Bs[j * 16 + l16][qd * 8];
            acc[j] = __builtin_amdgcn_mfma_f32_16x16x32_bf16(af, bfv, acc[j], 0, 0, 0);
        }
        __syncthreads();
    }
#pragma unroll
    for (int j = 0; j < 4; ++j) {
#pragma unroll
        for (int r = 0; r < 4; ++r) {
            int mm = m0 + wv * 16 + qd * 4 + r;   // C/D: row = quad*4 + reg
            if (mm < NN) {
                int nn = n0 + j * 16 + l16;       // col = lane&15
                float v = acc[j][r];
                if (BIAS) v += bias[nn];
                if (ELU) v = v > 0.f ? v : (__expf(v) - 1.f);
                Cout[(size_t)mm * N + nn] = v;
            }
        }
    }
}

// ---------------- epilogue: batch is SORTED -> segmented mean, no atomic storms ------
// bounds[g] = first node index with batch[n] >= g;  bounds[NG] = NN.
__global__ void bounds_k(const int* __restrict__ batch, int* __restrict__ bounds) {
    int g = threadIdx.x;          // 0..64, one block of 65 threads (padded to 128)
    if (g > NG) return;
    int lo = 0, hi = NN;
    while (lo < hi) {             // lower_bound(batch, g)
        int mid = (lo + hi) >> 1;
        if (batch[mid] < g) lo = mid + 1; else hi = mid;
    }
    bounds[g] = lo;
}

// elu(aggy + rr + b3) summed per contiguous graph run; flush once per run change.
__global__ __launch_bounds__(128) void finalize2_k(const float* __restrict__ aggy,
                                                   const float* __restrict__ rr,
                                                   const float* __restrict__ b3,
                                                   const int* __restrict__ batch,
                                                   float* __restrict__ outsum) {
    const int CH = 125;                        // 400 * 125 = 50000
    int n0 = blockIdx.x * CH;
    int c = threadIdx.x;
    float bias = b3[c];
    int g = batch[n0];
    float acc = 0.f;
    for (int i = 0; i < CH; ++i) {
        int n = n0 + i;
        int gn = batch[n];
        if (gn != g) {
            unsafeAtomicAdd(&outsum[(size_t)g * 128 + c], acc);
            acc = 0.f; g = gn;
        }
        size_t idx = (size_t)n * 128 + c;
        float v = aggy[idx] + rr[idx] + bias;
        v = v > 0.f ? v : (__expf(v) - 1.f);
        acc += v;
    }
    unsafeAtomicAdd(&outsum[(size_t)g * 128 + c], acc);
}

__global__ void divide_k(const int* __restrict__ bounds, float* __restrict__ out) {
    int i = blockIdx.x * 256 + threadIdx.x;
    if (i < NG * 128) {
        int g = i >> 7;
        float c = (float)(bounds[g + 1] - bounds[g]);
        out[i] /= fmaxf(c, 1.f);
    }
}

extern "C" void kernel_launch(void* const* d_in, const int* in_sizes, int n_in,
                              void* d_out, int out_size, void* d_ws, size_t ws_size,
                              hipStream_t stream) {
    const float* x       = (const float*)d_in[0];
    const int*   ei      = (const int*)d_in[1];
    const int*   batch   = (const int*)d_in[2];
    const float* w_rel1  = (const float*)d_in[3];
    const float* b_rel1  = (const float*)d_in[4];
    const float* w_root1 = (const float*)d_in[5];
    const float* w_rel2  = (const float*)d_in[6];
    const float* b_rel2  = (const float*)d_in[7];
    const float* w_root2 = (const float*)d_in[8];
    const float* w_rel3  = (const float*)d_in[9];
    const float* b_rel3  = (const float*)d_in[10];
    const float* w_root3 = (const float*)d_in[11];
    const int* esrc = ei;
    const int* edst = ei + NE;

    // workspace layout (fp32): A[NN*128] B[NN*128] C[NN*256], then ints
    float* A = (float*)d_ws;
    float* B = A + (size_t)NN * 128;
    float* C = B + (size_t)NN * 128;
    int* rowptr = (int*)(C + (size_t)NN * 256);
    int* cursor = rowptr + (NN + 1);
    int* colsrc = cursor + NN;
    int* bounds = colsrc + NE;      // NG+1 ints
    float* outp = (float*)d_out;

    // --- CSR build (per launch; same work every call) ---
    hipMemsetAsync(cursor, 0, NN * sizeof(int), stream);
    count_k<<<(NE + 255) / 256, 256, 0, stream>>>(edst, cursor);
    scan_k<<<1, 1024, 0, stream>>>(cursor, rowptr);
    copy_k<<<(NN + 255) / 256, 256, 0, stream>>>(rowptr, cursor);
    fill_k<<<(NE + 255) / 256, 256, 0, stream>>>(esrc, edst, cursor, colsrc);

    dim3 g2(782, 2), g4(782, 4);

    // L1: h1 = elu([agg(x) | x] @ [w_rel1; w_root1] + b1)    -> B
    agg_k<<<NN / 4, 256, 0, stream>>>(x, rowptr, colsrc, A);
    gemm_k<128, 128, true, true, true><<<g2, 256, 0, stream>>>(A, x, w_rel1, w_root1, b_rel1, B);

    // L2: h2 = elu([agg(h1) | h1] @ [w_rel2; w_root2] + b2)  -> C
    agg_k<<<NN / 4, 256, 0, stream>>>(B, rowptr, colsrc, A);
    gemm_k<128, 256, true, true, true><<<g4, 256, 0, stream>>>(A, B, w_rel2, w_root2, b_rel2, C);

    // L3: y = h2@w_rel3 -> A ; r = h2@w_root3 -> B ; agg(y) -> C(front)
    gemm_k<256, 128, false, false, false><<<g2, 256, 0, stream>>>(C, nullptr, w_rel3, nullptr, nullptr, A);
    gemm_k<256, 128, false, false, false><<<g2, 256, 0, stream>>>(C, nullptr, w_root3, nullptr, nullptr, B);
    agg_k<<<NN / 4, 256, 0, stream>>>(A, rowptr, colsrc, C);

    // scatter_mean (batch sorted -> segmented reduction)
    hipMemsetAsync(outp, 0, NG * 128 * sizeof(float), stream);
    bounds_k<<<1, 128, 0, stream>>>(batch, bounds);
    finalize2_k<<<NN / 125, 128, 0, stream>>>(C, B, b_rel3, batch, outp);
    divide_k<<<(NG * 128 + 255) / 256, 256, 0, stream>>>(bounds, outp);
}

// Round 3
// 534.248 us; speedup vs baseline: 1.4901x; 1.1939x over previous
//
#include <hip/hip_runtime.h>
#include <math.h>

#define NN 50000
#define NE 800000
#define NG 64
#define NB 196   // ceil(NN/256)

typedef __attribute__((ext_vector_type(8))) __bf16 bf16x8;
typedef __attribute__((ext_vector_type(8))) short short8;
typedef __attribute__((ext_vector_type(4))) float f32x4;

__device__ inline unsigned short f2bf(float f) {
    unsigned int u = __float_as_uint(f);
    u += 0x7fffu + ((u >> 16) & 1u);   // round-to-nearest-even
    return (unsigned short)(u >> 16);
}

// ---------------- CSR build ----------------
__global__ void count_k(const int* __restrict__ dst, int* __restrict__ cnt) {
    int e = blockIdx.x * 256 + threadIdx.x;
    if (e < NE) atomicAdd(&cnt[dst[e]], 1);
}

// 196 blocks: per-block sum of 256 counts
__global__ __launch_bounds__(256) void bsum_k(const int* __restrict__ cnt,
                                              int* __restrict__ bsum) {
    int i = blockIdx.x * 256 + threadIdx.x;
    int v = (i < NN) ? cnt[i] : 0;
    for (int off = 32; off; off >>= 1) v += __shfl_xor(v, off, 64);
    __shared__ int ws[4];
    if ((threadIdx.x & 63) == 0) ws[threadIdx.x >> 6] = v;
    __syncthreads();
    if (threadIdx.x == 0) bsum[blockIdx.x] = ws[0] + ws[1] + ws[2] + ws[3];
}

// 1 block: exclusive scan of 196 block sums
__global__ __launch_bounds__(256) void bscan_k(const int* __restrict__ bsum,
                                               int* __restrict__ boff) {
    __shared__ int s[256];
    int t = threadIdx.x;
    int v = (t < NB) ? bsum[t] : 0;
    s[t] = v; __syncthreads();
    for (int off = 1; off < 256; off <<= 1) {
        int u = (t >= off) ? s[t - off] : 0;
        __syncthreads(); s[t] += u; __syncthreads();
    }
    boff[t] = (t == 0) ? 0 : s[t - 1];
}

// 196 blocks: block-local exclusive scan + block offset -> rowptr & cursor
__global__ __launch_bounds__(256) void rowptr_k(const int* __restrict__ cnt,
                                                const int* __restrict__ boff,
                                                int* __restrict__ rowptr,
                                                int* __restrict__ cursor) {
    int t = threadIdx.x;
    int i = blockIdx.x * 256 + t;
    int v = (i < NN) ? cnt[i] : 0;
    __shared__ int s[256];
    s[t] = v; __syncthreads();
    for (int off = 1; off < 256; off <<= 1) {
        int u = (t >= off) ? s[t - off] : 0;
        __syncthreads(); s[t] += u; __syncthreads();
    }
    int excl = boff[blockIdx.x] + s[t] - v;
    if (i < NN) { rowptr[i] = excl; cursor[i] = excl; }
    if (i == 0) rowptr[NN] = NE;
}

__global__ void fill_k(const int* __restrict__ src, const int* __restrict__ dst,
                       int* __restrict__ cursor, int* __restrict__ colsrc) {
    int e = blockIdx.x * 256 + threadIdx.x;
    if (e < NE) {
        int d = dst[e];
        int pos = atomicAdd(&cursor[d], 1);
        colsrc[pos] = src[e];
    }
}

// ---------------- edge aggregation (CSR, one wave per node, d=128) ----------------
__global__ __launch_bounds__(256) void agg_k(const float* __restrict__ feat,
                                             const int* __restrict__ rowptr,
                                             const int* __restrict__ colsrc,
                                             float* __restrict__ out) {
    int node = __builtin_amdgcn_readfirstlane((int)(blockIdx.x * 4 + (threadIdx.x >> 6)));
    int lane = threadIdx.x & 63;
    int beg = rowptr[node], end = rowptr[node + 1];
    float2 acc = make_float2(0.f, 0.f);
    for (int e = beg; e < end; ++e) {
        int s = colsrc[e];
        float2 v = *(const float2*)&feat[(size_t)s * 128 + lane * 2];
        acc.x += v.x; acc.y += v.y;
    }
    *(float2*)&out[(size_t)node * 128 + lane * 2] = acc;
}

// ---------------- fused GEMM via bf16 MFMA ----------------
// A: [M,KA] fp32 row-major. TWO: virtual K=2*KA concat [A1|A2] with W=[W1;W2].
// SPLIT (TWO=false, N=256): virtual W = [W1 | W2] column-concat ([KA,128] each);
// output cols 0..127 -> Cout, 128..255 -> Cout2 (each [M,128]).
template <int KA, int N, bool TWO, bool BIAS, bool ELU, bool SPLIT>
__global__ __launch_bounds__(256) void gemm_k(const float* __restrict__ A1,
                                              const float* __restrict__ A2,
                                              const float* __restrict__ W1,
                                              const float* __restrict__ W2,
                                              const float* __restrict__ bias,
                                              float* __restrict__ Cout,
                                              float* __restrict__ Cout2) {
    constexpr int KTOT = TWO ? 2 * KA : KA;
    __shared__ __attribute__((aligned(16))) unsigned short As[64][40];  // [m][k] bf16, +8 pad
    __shared__ __attribute__((aligned(16))) unsigned short Bs[64][40];  // [n][k] bf16 (W^T)
    const int t = threadIdx.x;
    const int m0 = blockIdx.x * 64;
    const int n0 = blockIdx.y * 64;
    const int wv = t >> 6, lane = t & 63, qd = lane >> 4, l16 = lane & 15;
    f32x4 acc[4] = {};

    const int arow = t >> 2;           // 0..63
    const int akk  = (t & 3) << 3;     // 0,8,16,24
    const int wkl  = t >> 3;           // 0..31
    const int wng  = (t & 7) << 3;     // 0..56
    const int gm = m0 + arow;

    for (int k0 = 0; k0 < KTOT; k0 += 32) {
        {   // stage A tile 64x32 (fp32 -> bf16)
            int kabs = k0 + akk;
            const float* src = (TWO && kabs >= KA) ? (A2 + (size_t)gm * KA + (kabs - KA))
                                                   : (A1 + (size_t)gm * KA + kabs);
            float4 v0 = make_float4(0.f, 0.f, 0.f, 0.f), v1 = v0;
            if (gm < NN) { v0 = *(const float4*)src; v1 = *(const float4*)(src + 4); }
            short8 sv;
            sv[0] = (short)f2bf(v0.x); sv[1] = (short)f2bf(v0.y);
            sv[2] = (short)f2bf(v0.z); sv[3] = (short)f2bf(v0.w);
            sv[4] = (short)f2bf(v1.x); sv[5] = (short)f2bf(v1.y);
            sv[6] = (short)f2bf(v1.z); sv[7] = (short)f2bf(v1.w);
            *(short8*)&As[arow][akk] = sv;
        }
        {   // stage W tile 32x64, transposed into Bs[n][k]
            int kabs = k0 + wkl;
            const float* src;
            if (SPLIT) {
                const float* wsel = (n0 < 128) ? W1 : W2;
                src = wsel + (size_t)kabs * 128 + ((n0 + wng) & 127);
            } else if (TWO && kabs >= KA) {
                src = W2 + (size_t)(kabs - KA) * N + n0 + wng;
            } else {
                src = W1 + (size_t)kabs * N + n0 + wng;
            }
            float4 v0 = *(const float4*)src;
            float4 v1 = *(const float4*)(src + 4);
            Bs[wng + 0][wkl] = f2bf(v0.x); Bs[wng + 1][wkl] = f2bf(v0.y);
            Bs[wng + 2][wkl] = f2bf(v0.z); Bs[wng + 3][wkl] = f2bf(v0.w);
            Bs[wng + 4][wkl] = f2bf(v1.x); Bs[wng + 5][wkl] = f2bf(v1.y);
            Bs[wng + 6][wkl] = f2bf(v1.z); Bs[wng + 7][wkl] = f2bf(v1.w);
        }
        __syncthreads();
        bf16x8 af = *(const bf16x8*)&As[wv * 16 + l16][qd * 8];
#pragma unroll
        for (int j = 0; j < 4; ++j) {
            bf16x8 bfv = *(const bf16x8*)&Bs[j * 16 + l16][qd * 8];
            acc[j] = __builtin_amdgcn_mfma_f32_16x16x32_bf16(af, bfv, acc[j], 0, 0, 0);
        }
        __syncthreads();
    }
#pragma unroll
    for (int j = 0; j < 4; ++j) {
#pragma unroll
        for (int r = 0; r < 4; ++r) {
            int mm = m0 + wv * 16 + qd * 4 + r;   // C/D: row = quad*4 + reg
            if (mm < NN) {
                int nn = n0 + j * 16 + l16;       // col = lane&15
                float v = acc[j][r];
                if (BIAS) v += bias[nn];
                if (ELU) v = v > 0.f ? v : (__expf(v) - 1.f);
                if (SPLIT) {
                    float* dst = (nn < 128) ? Cout : Cout2;
                    dst[(size_t)mm * 128 + (nn & 127)] = v;
                } else {
                    Cout[(size_t)mm * N + nn] = v;
                }
            }
        }
    }
}

// ---------------- epilogue: batch is SORTED -> segmented mean ----------------
__global__ void bounds_k(const int* __restrict__ batch, int* __restrict__ bounds) {
    int g = threadIdx.x;
    if (g > NG) return;
    int lo = 0, hi = NN;
    while (lo < hi) {
        int mid = (lo + hi) >> 1;
        if (batch[mid] < g) lo = mid + 1; else hi = mid;
    }
    bounds[g] = lo;
}

__global__ __launch_bounds__(128) void finalize2_k(const float* __restrict__ aggy,
                                                   const float* __restrict__ rr,
                                                   const float* __restrict__ b3,
                                                   const int* __restrict__ batch,
                                                   float* __restrict__ outsum) {
    const int CH = 125;                        // 400 * 125 = 50000
    int n0 = blockIdx.x * CH;
    int c = threadIdx.x;
    float bias = b3[c];
    int g = batch[n0];
    float acc = 0.f;
    for (int i = 0; i < CH; ++i) {
        int n = n0 + i;
        int gn = batch[n];
        if (gn != g) {
            unsafeAtomicAdd(&outsum[(size_t)g * 128 + c], acc);
            acc = 0.f; g = gn;
        }
        size_t idx = (size_t)n * 128 + c;
        float v = aggy[idx] + rr[idx] + bias;
        v = v > 0.f ? v : (__expf(v) - 1.f);
        acc += v;
    }
    unsafeAtomicAdd(&outsum[(size_t)g * 128 + c], acc);
}

__global__ void divide_k(const int* __restrict__ bounds, float* __restrict__ out) {
    int i = blockIdx.x * 256 + threadIdx.x;
    if (i < NG * 128) {
        int g = i >> 7;
        float c = (float)(bounds[g + 1] - bounds[g]);
        out[i] /= fmaxf(c, 1.f);
    }
}

extern "C" void kernel_launch(void* const* d_in, const int* in_sizes, int n_in,
                              void* d_out, int out_size, void* d_ws, size_t ws_size,
                              hipStream_t stream) {
    const float* x       = (const float*)d_in[0];
    const int*   ei      = (const int*)d_in[1];
    const int*   batch   = (const int*)d_in[2];
    const float* w_rel1  = (const float*)d_in[3];
    const float* b_rel1  = (const float*)d_in[4];
    const float* w_root1 = (const float*)d_in[5];
    const float* w_rel2  = (const float*)d_in[6];
    const float* b_rel2  = (const float*)d_in[7];
    const float* w_root2 = (const float*)d_in[8];
    const float* w_rel3  = (const float*)d_in[9];
    const float* b_rel3  = (const float*)d_in[10];
    const float* w_root3 = (const float*)d_in[11];
    const int* esrc = ei;
    const int* edst = ei + NE;

    // workspace layout (fp32): A[NN*128] B[NN*128] C[NN*256], then ints
    float* A = (float*)d_ws;
    float* B = A + (size_t)NN * 128;
    float* C = B + (size_t)NN * 128;
    int* rowptr = (int*)(C + (size_t)NN * 256);
    int* cnt    = rowptr + (NN + 1);
    int* cursor = cnt + NN;
    int* colsrc = cursor + NN;
    int* bsum   = colsrc + NE;      // 256
    int* boff   = bsum + 256;       // 256
    int* bounds = boff + 256;       // NG+1
    float* outp = (float*)d_out;

    // --- CSR build (hierarchical scan, all phases parallel+coalesced) ---
    hipMemsetAsync(cnt, 0, NN * sizeof(int), stream);
    count_k<<<(NE + 255) / 256, 256, 0, stream>>>(edst, cnt);
    bsum_k<<<NB, 256, 0, stream>>>(cnt, bsum);
    bscan_k<<<1, 256, 0, stream>>>(bsum, boff);
    rowptr_k<<<NB, 256, 0, stream>>>(cnt, boff, rowptr, cursor);
    fill_k<<<(NE + 255) / 256, 256, 0, stream>>>(esrc, edst, cursor, colsrc);

    dim3 g2(782, 2), g4(782, 4);

    // L1: h1 = elu([agg(x) | x] @ [w_rel1; w_root1] + b1)    -> B
    agg_k<<<NN / 4, 256, 0, stream>>>(x, rowptr, colsrc, A);
    gemm_k<128, 128, true, true, true, false><<<g2, 256, 0, stream>>>(A, x, w_rel1, w_root1, b_rel1, B, nullptr);

    // L2: h2 = elu([agg(h1) | h1] @ [w_rel2; w_root2] + b2)  -> C
    agg_k<<<NN / 4, 256, 0, stream>>>(B, rowptr, colsrc, A);
    gemm_k<128, 256, true, true, true, false><<<g4, 256, 0, stream>>>(A, B, w_rel2, w_root2, b_rel2, C, nullptr);

    // L3: one dispatch: y = h2@w_rel3 -> A, r = h2@w_root3 -> B ; then agg(y) -> C
    gemm_k<256, 256, false, false, false, true><<<g4, 256, 0, stream>>>(C, nullptr, w_rel3, w_root3, nullptr, A, B);
    agg_k<<<NN / 4, 256, 0, stream>>>(A, rowptr, colsrc, C);

    // scatter_mean (batch sorted -> segmented reduction)
    hipMemsetAsync(outp, 0, NG * 128 * sizeof(float), stream);
    bounds_k<<<1, 128, 0, stream>>>(batch, bounds);
    finalize2_k<<<NN / 125, 128, 0, stream>>>(C, B, b_rel3, batch, outp);
    divide_k<<<(NG * 128 + 255) / 256, 256, 0, stream>>>(bounds, outp);
}

// Round 4
// 455.084 us; speedup vs baseline: 1.7493x; 1.1740x over previous
//
#include <hip/hip_runtime.h>
#include <math.h>

#define NN 50000
#define NE 800000
#define NG 64
#define NB 196   // ceil(NN/256)

typedef __attribute__((ext_vector_type(8))) __bf16 bf16x8;
typedef __attribute__((ext_vector_type(8))) short short8;
typedef __attribute__((ext_vector_type(4))) float f32x4;

__device__ inline unsigned short f2bf(float f) {
    unsigned int u = __float_as_uint(f);
    u += 0x7fffu + ((u >> 16) & 1u);   // round-to-nearest-even
    return (unsigned short)(u >> 16);
}
__device__ inline float bflo(unsigned int v) { return __uint_as_float(v << 16); }
__device__ inline float bfhi(unsigned int v) { return __uint_as_float(v & 0xffff0000u); }

// ---------------- fp32 -> bf16 convert (x only) ----------------
__global__ __launch_bounds__(256) void cvt_k(const float* __restrict__ in,
                                             unsigned short* __restrict__ outp) {
    int i = blockIdx.x * 256 + threadIdx.x;      // 4 elems per thread
    if (i < NN * 32) {
        float4 v = ((const float4*)in)[i];
        unsigned int p0 = ((unsigned int)f2bf(v.y) << 16) | f2bf(v.x);
        unsigned int p1 = ((unsigned int)f2bf(v.w) << 16) | f2bf(v.z);
        ((uint2*)outp)[i] = make_uint2(p0, p1);
    }
}

// ---------------- CSR build ----------------
__global__ void count_k(const int* __restrict__ dst, int* __restrict__ cnt) {
    int e = blockIdx.x * 256 + threadIdx.x;
    if (e < NE) atomicAdd(&cnt[dst[e]], 1);
}

__global__ __launch_bounds__(256) void bsum_k(const int* __restrict__ cnt,
                                              int* __restrict__ bsum) {
    int i = blockIdx.x * 256 + threadIdx.x;
    int v = (i < NN) ? cnt[i] : 0;
    for (int off = 32; off; off >>= 1) v += __shfl_xor(v, off, 64);
    __shared__ int ws[4];
    if ((threadIdx.x & 63) == 0) ws[threadIdx.x >> 6] = v;
    __syncthreads();
    if (threadIdx.x == 0) bsum[blockIdx.x] = ws[0] + ws[1] + ws[2] + ws[3];
}

__global__ __launch_bounds__(256) void bscan_k(const int* __restrict__ bsum,
                                               int* __restrict__ boff) {
    __shared__ int s[256];
    int t = threadIdx.x;
    int v = (t < NB) ? bsum[t] : 0;
    s[t] = v; __syncthreads();
    for (int off = 1; off < 256; off <<= 1) {
        int u = (t >= off) ? s[t - off] : 0;
        __syncthreads(); s[t] += u; __syncthreads();
    }
    boff[t] = (t == 0) ? 0 : s[t - 1];
}

__global__ __launch_bounds__(256) void rowptr_k(const int* __restrict__ cnt,
                                                const int* __restrict__ boff,
                                                int* __restrict__ rowptr,
                                                int* __restrict__ cursor) {
    int t = threadIdx.x;
    int i = blockIdx.x * 256 + t;
    int v = (i < NN) ? cnt[i] : 0;
    __shared__ int s[256];
    s[t] = v; __syncthreads();
    for (int off = 1; off < 256; off <<= 1) {
        int u = (t >= off) ? s[t - off] : 0;
        __syncthreads(); s[t] += u; __syncthreads();
    }
    int excl = boff[blockIdx.x] + s[t] - v;
    if (i < NN) { rowptr[i] = excl; cursor[i] = excl; }
    if (i == 0) rowptr[NN] = NE;
}

__global__ void fill_k(const int* __restrict__ src, const int* __restrict__ dst,
                       int* __restrict__ cursor, int* __restrict__ colsrc) {
    int e = blockIdx.x * 256 + threadIdx.x;
    if (e < NE) {
        int d = dst[e];
        int pos = atomicAdd(&cursor[d], 1);
        colsrc[pos] = src[e];
    }
}

// ---------------- edge aggregation, bf16 features (256 B/row) ----------------
__global__ __launch_bounds__(256) void aggb_k(const unsigned short* __restrict__ feat,
                                              const int* __restrict__ rowptr,
                                              const int* __restrict__ colsrc,
                                              unsigned short* __restrict__ outp) {
    int node = __builtin_amdgcn_readfirstlane((int)(blockIdx.x * 4 + (threadIdx.x >> 6)));
    int lane = threadIdx.x & 63;
    int beg = rowptr[node], end = rowptr[node + 1];
    float ax = 0.f, ay = 0.f;
    int e = beg;
    for (; e + 2 <= end; e += 2) {
        int s0 = colsrc[e], s1 = colsrc[e + 1];
        unsigned int v0 = *(const unsigned int*)&feat[(size_t)s0 * 128 + lane * 2];
        unsigned int v1 = *(const unsigned int*)&feat[(size_t)s1 * 128 + lane * 2];
        ax += bflo(v0); ay += bfhi(v0);
        ax += bflo(v1); ay += bfhi(v1);
    }
    if (e < end) {
        unsigned int v0 = *(const unsigned int*)&feat[(size_t)colsrc[e] * 128 + lane * 2];
        ax += bflo(v0); ay += bfhi(v0);
    }
    unsigned int p = ((unsigned int)f2bf(ay) << 16) | f2bf(ax);
    *(unsigned int*)&outp[(size_t)node * 128 + lane * 2] = p;
}

// ---------------- fused GEMM via bf16 MFMA ----------------
// A: [M,KA] bf16 row-major. TWO: virtual K=2*KA concat [A1|A2], W=[W1;W2] fp32.
// SPLIT (N=256): W = [W1|W2] col-concat ([KA,128] fp32 each); cols 0..127 -> Cout,
// 128..255 -> Cout2 (each [M,128] bf16).
template <int KA, int N, bool TWO, bool BIAS, bool ELU, bool SPLIT>
__global__ __launch_bounds__(256) void gemm_k(const unsigned short* __restrict__ A1,
                                              const unsigned short* __restrict__ A2,
                                              const float* __restrict__ W1,
                                              const float* __restrict__ W2,
                                              const float* __restrict__ bias,
                                              unsigned short* __restrict__ Cout,
                                              unsigned short* __restrict__ Cout2) {
    constexpr int KTOT = TWO ? 2 * KA : KA;
    __shared__ __attribute__((aligned(16))) unsigned short As[64][40];  // [m][k], +8 pad
    __shared__ __attribute__((aligned(16))) unsigned short Bs[64][40];  // [n][k] (W^T)
    const int t = threadIdx.x;
    const int m0 = blockIdx.x * 64;
    const int n0 = blockIdx.y * 64;
    const int wv = t >> 6, lane = t & 63, qd = lane >> 4, l16 = lane & 15;
    f32x4 acc[4] = {};

    const int arow = t >> 2;           // 0..63
    const int akk  = (t & 3) << 3;     // 0,8,16,24
    const int wkl  = t >> 3;           // 0..31
    const int wng  = (t & 7) << 3;     // 0..56
    const int gm = m0 + arow;

    for (int k0 = 0; k0 < KTOT; k0 += 32) {
        {   // stage A tile 64x32 (bf16 direct, 16 B per thread)
            int kabs = k0 + akk;
            const unsigned short* src = (TWO && kabs >= KA)
                ? (A2 + (size_t)gm * KA + (kabs - KA))
                : (A1 + (size_t)gm * KA + kabs);
            short8 sv = {};
            if (gm < NN) sv = *(const short8*)src;
            *(short8*)&As[arow][akk] = sv;
        }
        {   // stage W tile 32x64 (fp32 -> bf16), transposed into Bs[n][k]
            int kabs = k0 + wkl;
            const float* src;
            if (SPLIT) {
                const float* wsel = (n0 < 128) ? W1 : W2;
                src = wsel + (size_t)kabs * 128 + ((n0 + wng) & 127);
            } else if (TWO && kabs >= KA) {
                src = W2 + (size_t)(kabs - KA) * N + n0 + wng;
            } else {
                src = W1 + (size_t)kabs * N + n0 + wng;
            }
            float4 v0 = *(const float4*)src;
            float4 v1 = *(const float4*)(src + 4);
            Bs[wng + 0][wkl] = f2bf(v0.x); Bs[wng + 1][wkl] = f2bf(v0.y);
            Bs[wng + 2][wkl] = f2bf(v0.z); Bs[wng + 3][wkl] = f2bf(v0.w);
            Bs[wng + 4][wkl] = f2bf(v1.x); Bs[wng + 5][wkl] = f2bf(v1.y);
            Bs[wng + 6][wkl] = f2bf(v1.z); Bs[wng + 7][wkl] = f2bf(v1.w);
        }
        __syncthreads();
        bf16x8 af = *(const bf16x8*)&As[wv * 16 + l16][qd * 8];
#pragma unroll
        for (int j = 0; j < 4; ++j) {
            bf16x8 bfv = *(const bf16x8*)&Bs[j * 16 + l16][qd * 8];
            acc[j] = __builtin_amdgcn_mfma_f32_16x16x32_bf16(af, bfv, acc[j], 0, 0, 0);
        }
        __syncthreads();
    }
#pragma unroll
    for (int j = 0; j < 4; ++j) {
#pragma unroll
        for (int r = 0; r < 4; ++r) {
            int mm = m0 + wv * 16 + qd * 4 + r;   // C/D: row = quad*4 + reg
            if (mm < NN) {
                int nn = n0 + j * 16 + l16;       // col = lane&15
                float v = acc[j][r];
                if (BIAS) v += bias[nn];
                if (ELU) v = v > 0.f ? v : (__expf(v) - 1.f);
                unsigned short b = f2bf(v);
                if (SPLIT) {
                    unsigned short* dst = (nn < 128) ? Cout : Cout2;
                    dst[(size_t)mm * 128 + (nn & 127)] = b;
                } else {
                    Cout[(size_t)mm * N + nn] = b;
                }
            }
        }
    }
}

// ---------------- epilogue: batch is SORTED -> segmented mean ----------------
__global__ void bounds_k(const int* __restrict__ batch, int* __restrict__ bounds) {
    int g = threadIdx.x;
    if (g > NG) return;
    int lo = 0, hi = NN;
    while (lo < hi) {
        int mid = (lo + hi) >> 1;
        if (batch[mid] < g) lo = mid + 1; else hi = mid;
    }
    bounds[g] = lo;
}

__global__ __launch_bounds__(128) void finalize2_k(const unsigned short* __restrict__ aggy,
                                                   const unsigned short* __restrict__ rr,
                                                   const float* __restrict__ b3,
                                                   const int* __restrict__ batch,
                                                   float* __restrict__ outsum) {
    const int CH = 125;                        // 400 * 125 = 50000
    int n0 = blockIdx.x * CH;
    int c = threadIdx.x;
    float bias = b3[c];
    int g = batch[n0];
    float acc = 0.f;
    for (int i = 0; i < CH; ++i) {
        int n = n0 + i;
        int gn = batch[n];
        if (gn != g) {
            unsafeAtomicAdd(&outsum[(size_t)g * 128 + c], acc);
            acc = 0.f; g = gn;
        }
        size_t idx = (size_t)n * 128 + c;
        float v = __uint_as_float((unsigned int)aggy[idx] << 16)
                + __uint_as_float((unsigned int)rr[idx] << 16) + bias;
        v = v > 0.f ? v : (__expf(v) - 1.f);
        acc += v;
    }
    unsafeAtomicAdd(&outsum[(size_t)g * 128 + c], acc);
}

__global__ void divide_k(const int* __restrict__ bounds, float* __restrict__ out) {
    int i = blockIdx.x * 256 + threadIdx.x;
    if (i < NG * 128) {
        int g = i >> 7;
        float c = (float)(bounds[g + 1] - bounds[g]);
        out[i] /= fmaxf(c, 1.f);
    }
}

extern "C" void kernel_launch(void* const* d_in, const int* in_sizes, int n_in,
                              void* d_out, int out_size, void* d_ws, size_t ws_size,
                              hipStream_t stream) {
    const float* x       = (const float*)d_in[0];
    const int*   ei      = (const int*)d_in[1];
    const int*   batch   = (const int*)d_in[2];
    const float* w_rel1  = (const float*)d_in[3];
    const float* b_rel1  = (const float*)d_in[4];
    const float* w_root1 = (const float*)d_in[5];
    const float* w_rel2  = (const float*)d_in[6];
    const float* b_rel2  = (const float*)d_in[7];
    const float* w_root2 = (const float*)d_in[8];
    const float* w_rel3  = (const float*)d_in[9];
    const float* b_rel3  = (const float*)d_in[10];
    const float* w_root3 = (const float*)d_in[11];
    const int* esrc = ei;
    const int* edst = ei + NE;

    // workspace: bf16 feature buffers then int arrays
    unsigned short* Ab = (unsigned short*)d_ws;          // [NN,128] agg out / y
    unsigned short* Bb = Ab + (size_t)NN * 128;          // [NN,128] h1 / r
    unsigned short* Cb = Bb + (size_t)NN * 128;          // [NN,256] h2 ; front reused for agg(y)
    unsigned short* xb = Cb + (size_t)NN * 256;          // [NN,128] x in bf16
    int* rowptr = (int*)(xb + (size_t)NN * 128);
    int* cnt    = rowptr + (NN + 1);
    int* cursor = cnt + NN;
    int* colsrc = cursor + NN;
    int* bsum   = colsrc + NE;      // 256
    int* boff   = bsum + 256;       // 256
    int* bounds = boff + 256;       // NG+1
    float* outp = (float*)d_out;

    // --- CSR build + x conversion ---
    hipMemsetAsync(cnt, 0, NN * sizeof(int), stream);
    cvt_k<<<(NN * 32 + 255) / 256, 256, 0, stream>>>(x, xb);
    count_k<<<(NE + 255) / 256, 256, 0, stream>>>(edst, cnt);
    bsum_k<<<NB, 256, 0, stream>>>(cnt, bsum);
    bscan_k<<<1, 256, 0, stream>>>(bsum, boff);
    rowptr_k<<<NB, 256, 0, stream>>>(cnt, boff, rowptr, cursor);
    fill_k<<<(NE + 255) / 256, 256, 0, stream>>>(esrc, edst, cursor, colsrc);

    dim3 g2(782, 2), g4(782, 4);

    // L1: h1 = elu([agg(x) | x] @ [w_rel1; w_root1] + b1)    -> Bb
    aggb_k<<<NN / 4, 256, 0, stream>>>(xb, rowptr, colsrc, Ab);
    gemm_k<128, 128, true, true, true, false><<<g2, 256, 0, stream>>>(Ab, xb, w_rel1, w_root1, b_rel1, Bb, nullptr);

    // L2: h2 = elu([agg(h1) | h1] @ [w_rel2; w_root2] + b2)  -> Cb
    aggb_k<<<NN / 4, 256, 0, stream>>>(Bb, rowptr, colsrc, Ab);
    gemm_k<128, 256, true, true, true, false><<<g4, 256, 0, stream>>>(Ab, Bb, w_rel2, w_root2, b_rel2, Cb, nullptr);

    // L3: y = h2@w_rel3 -> Ab, r = h2@w_root3 -> Bb (one dispatch); agg(y) -> Cb
    gemm_k<256, 256, false, false, false, true><<<g4, 256, 0, stream>>>(Cb, nullptr, w_rel3, w_root3, nullptr, Ab, Bb);
    aggb_k<<<NN / 4, 256, 0, stream>>>(Ab, rowptr, colsrc, Cb);

    // scatter_mean (batch sorted -> segmented reduction)
    hipMemsetAsync(outp, 0, NG * 128 * sizeof(float), stream);
    bounds_k<<<1, 128, 0, stream>>>(batch, bounds);
    finalize2_k<<<NN / 125, 128, 0, stream>>>(Cb, Bb, b_rel3, batch, outp);
    divide_k<<<(NG * 128 + 255) / 256, 256, 0, stream>>>(bounds, outp);
}

// Round 5
// 416.906 us; speedup vs baseline: 1.9095x; 1.0916x over previous
//
#include <hip/hip_runtime.h>
#include <math.h>

#define NN 50000
#define NE 800000
#define NG 64
#define NBK 196          // buckets of 256 nodes: ceil(50000/256)
#define ECH 4082         // edges per hist/scatter block: 196*4082 >= 800000

typedef __attribute__((ext_vector_type(8))) __bf16 bf16x8;
typedef __attribute__((ext_vector_type(8))) short short8;
typedef __attribute__((ext_vector_type(4))) float f32x4;

__device__ inline unsigned short f2bf(float f) {
    unsigned int u = __float_as_uint(f);
    u += 0x7fffu + ((u >> 16) & 1u);   // round-to-nearest-even
    return (unsigned short)(u >> 16);
}
__device__ inline float bflo(unsigned int v) { return __uint_as_float(v << 16); }
__device__ inline float bfhi(unsigned int v) { return __uint_as_float(v & 0xffff0000u); }

// ---------------- fp32 -> bf16 convert (x only) ----------------
__global__ __launch_bounds__(256) void cvt_k(const float* __restrict__ in,
                                             unsigned short* __restrict__ outp) {
    int i = blockIdx.x * 256 + threadIdx.x;      // 4 elems per thread
    if (i < NN * 32) {
        float4 v = ((const float4*)in)[i];
        unsigned int p0 = ((unsigned int)f2bf(v.y) << 16) | f2bf(v.x);
        unsigned int p1 = ((unsigned int)f2bf(v.w) << 16) | f2bf(v.z);
        ((uint2*)outp)[i] = make_uint2(p0, p1);
    }
}

// ---------------- CSR build: block-private counting sort ----------------
// Phase 1: per-block bucket histogram. Block k handles edges [k*ECH,(k+1)*ECH).
__global__ __launch_bounds__(256) void hist_k(const int* __restrict__ dst,
                                              int* __restrict__ H) {
    __shared__ int h[NBK];
    int t = threadIdx.x, k = blockIdx.x;
    if (t < NBK) h[t] = 0;
    __syncthreads();
    int e0 = k * ECH, e1 = min(NE, e0 + ECH);
    for (int e = e0 + t; e < e1; e += 256) atomicAdd(&h[dst[e] >> 8], 1);
    __syncthreads();
    if (t < NBK) H[t * NBK + k] = h[t];          // bucket-major layout
}

// Phase 2: exclusive scan of H (NBK*NBK = 38416 values), one block.
__global__ __launch_bounds__(1024) void scanH_k(const int* __restrict__ H,
                                                int* __restrict__ S) {
    const int TOT = NBK * NBK, CH = 38;          // 1024*38 = 38912 >= 38416
    __shared__ int ps[1024];
    int t = threadIdx.x, base = t * CH;
    int s = 0;
    for (int i = 0; i < CH; ++i) { int idx = base + i; if (idx < TOT) s += H[idx]; }
    ps[t] = s; __syncthreads();
    for (int off = 1; off < 1024; off <<= 1) {
        int u = (t >= off) ? ps[t - off] : 0;
        __syncthreads(); ps[t] += u; __syncthreads();
    }
    int pre = (t == 0) ? 0 : ps[t - 1];
    for (int i = 0; i < CH; ++i) {
        int idx = base + i;
        if (idx < TOT) { int v = H[idx]; S[idx] = pre; pre += v; }
    }
}

// Phase 3: scatter edges into bucket-major tmp using exclusive per-(bucket,block)
// slots -> privately-owned write regions (no cross-XCD line sharing).
// tmp entry packs (dst&255)<<16 | src   (src < 50000 < 2^16).
__global__ __launch_bounds__(256) void scatter_k(const int* __restrict__ src,
                                                 const int* __restrict__ dst,
                                                 const int* __restrict__ S,
                                                 int* __restrict__ tmp) {
    __shared__ int cur[NBK];
    int t = threadIdx.x, k = blockIdx.x;
    if (t < NBK) cur[t] = S[t * NBK + k];
    __syncthreads();
    int e0 = k * ECH, e1 = min(NE, e0 + ECH);
    for (int e = e0 + t; e < e1; e += 256) {
        int d = dst[e];
        int p = atomicAdd(&cur[d >> 8], 1);
        tmp[p] = ((d & 255) << 16) | src[e];
    }
}

// Phase 4: per-bucket node-sort (bucket range ~16 KB, single-XCD L2 resident).
// Also emits rowptr (incl. rowptr[NN]=NE automatically).
__global__ __launch_bounds__(256) void csr_k(const int* __restrict__ tmp,
                                             const int* __restrict__ S,
                                             int* __restrict__ rowptr,
                                             int* __restrict__ colsrc) {
    __shared__ int hist[256], off[256], cur[256];
    int t = threadIdx.x, b = blockIdx.x;
    int base = S[b * NBK];
    int next = (b < NBK - 1) ? S[(b + 1) * NBK] : NE;
    int cntb = next - base;
    hist[t] = 0;
    __syncthreads();
    for (int i = t; i < cntb; i += 256) atomicAdd(&hist[tmp[base + i] >> 16], 1);
    __syncthreads();
    int v = hist[t];
    off[t] = v; __syncthreads();
    for (int o = 1; o < 256; o <<= 1) {                 // inclusive scan
        int u = (t >= o) ? off[t - o] : 0;
        __syncthreads(); off[t] += u; __syncthreads();
    }
    int excl = off[t] - v;                              // exclusive
    int node = b * 256 + t;
    if (node <= NN) rowptr[node] = base + excl;
    cur[t] = excl;
    __syncthreads();
    for (int i = t; i < cntb; i += 256) {
        int e = tmp[base + i];
        int p = atomicAdd(&cur[e >> 16], 1);
        colsrc[base + p] = e & 0xffff;
    }
}

// ---------------- edge aggregation, bf16 features (256 B/row) ----------------
__global__ __launch_bounds__(256) void aggb_k(const unsigned short* __restrict__ feat,
                                              const int* __restrict__ rowptr,
                                              const int* __restrict__ colsrc,
                                              unsigned short* __restrict__ outp) {
    int node = __builtin_amdgcn_readfirstlane((int)(blockIdx.x * 4 + (threadIdx.x >> 6)));
    int lane = threadIdx.x & 63;
    int beg = rowptr[node], end = rowptr[node + 1];
    float ax = 0.f, ay = 0.f;
    int e = beg;
    for (; e + 2 <= end; e += 2) {
        int s0 = colsrc[e], s1 = colsrc[e + 1];
        unsigned int v0 = *(const unsigned int*)&feat[(size_t)s0 * 128 + lane * 2];
        unsigned int v1 = *(const unsigned int*)&feat[(size_t)s1 * 128 + lane * 2];
        ax += bflo(v0); ay += bfhi(v0);
        ax += bflo(v1); ay += bfhi(v1);
    }
    if (e < end) {
        unsigned int v0 = *(const unsigned int*)&feat[(size_t)colsrc[e] * 128 + lane * 2];
        ax += bflo(v0); ay += bfhi(v0);
    }
    unsigned int p = ((unsigned int)f2bf(ay) << 16) | f2bf(ax);
    *(unsigned int*)&outp[(size_t)node * 128 + lane * 2] = p;
}

// ---------------- fused GEMM via bf16 MFMA ----------------
template <int KA, int N, bool TWO, bool BIAS, bool ELU, bool SPLIT>
__global__ __launch_bounds__(256) void gemm_k(const unsigned short* __restrict__ A1,
                                              const unsigned short* __restrict__ A2,
                                              const float* __restrict__ W1,
                                              const float* __restrict__ W2,
                                              const float* __restrict__ bias,
                                              unsigned short* __restrict__ Cout,
                                              unsigned short* __restrict__ Cout2) {
    constexpr int KTOT = TWO ? 2 * KA : KA;
    __shared__ __attribute__((aligned(16))) unsigned short As[64][40];
    __shared__ __attribute__((aligned(16))) unsigned short Bs[64][40];
    const int t = threadIdx.x;
    const int m0 = blockIdx.x * 64;
    const int n0 = blockIdx.y * 64;
    const int wv = t >> 6, lane = t & 63, qd = lane >> 4, l16 = lane & 15;
    f32x4 acc[4] = {};

    const int arow = t >> 2;
    const int akk  = (t & 3) << 3;
    const int wkl  = t >> 3;
    const int wng  = (t & 7) << 3;
    const int gm = m0 + arow;

    for (int k0 = 0; k0 < KTOT; k0 += 32) {
        {   // stage A tile 64x32 (bf16 direct, 16 B per thread)
            int kabs = k0 + akk;
            const unsigned short* src = (TWO && kabs >= KA)
                ? (A2 + (size_t)gm * KA + (kabs - KA))
                : (A1 + (size_t)gm * KA + kabs);
            short8 sv = {};
            if (gm < NN) sv = *(const short8*)src;
            *(short8*)&As[arow][akk] = sv;
        }
        {   // stage W tile 32x64 (fp32 -> bf16), transposed into Bs[n][k]
            int kabs = k0 + wkl;
            const float* src;
            if (SPLIT) {
                const float* wsel = (n0 < 128) ? W1 : W2;
                src = wsel + (size_t)kabs * 128 + ((n0 + wng) & 127);
            } else if (TWO && kabs >= KA) {
                src = W2 + (size_t)(kabs - KA) * N + n0 + wng;
            } else {
                src = W1 + (size_t)kabs * N + n0 + wng;
            }
            float4 v0 = *(const float4*)src;
            float4 v1 = *(const float4*)(src + 4);
            Bs[wng + 0][wkl] = f2bf(v0.x); Bs[wng + 1][wkl] = f2bf(v0.y);
            Bs[wng + 2][wkl] = f2bf(v0.z); Bs[wng + 3][wkl] = f2bf(v0.w);
            Bs[wng + 4][wkl] = f2bf(v1.x); Bs[wng + 5][wkl] = f2bf(v1.y);
            Bs[wng + 6][wkl] = f2bf(v1.z); Bs[wng + 7][wkl] = f2bf(v1.w);
        }
        __syncthreads();
        bf16x8 af = *(const bf16x8*)&As[wv * 16 + l16][qd * 8];
#pragma unroll
        for (int j = 0; j < 4; ++j) {
            bf16x8 bfv = *(const bf16x8*)&Bs[j * 16 + l16][qd * 8];
            acc[j] = __builtin_amdgcn_mfma_f32_16x16x32_bf16(af, bfv, acc[j], 0, 0, 0);
        }
        __syncthreads();
    }
#pragma unroll
    for (int j = 0; j < 4; ++j) {
#pragma unroll
        for (int r = 0; r < 4; ++r) {
            int mm = m0 + wv * 16 + qd * 4 + r;
            if (mm < NN) {
                int nn = n0 + j * 16 + l16;
                float v = acc[j][r];
                if (BIAS) v += bias[nn];
                if (ELU) v = v > 0.f ? v : (__expf(v) - 1.f);
                unsigned short b = f2bf(v);
                if (SPLIT) {
                    unsigned short* dst = (nn < 128) ? Cout : Cout2;
                    dst[(size_t)mm * 128 + (nn & 127)] = b;
                } else {
                    Cout[(size_t)mm * N + nn] = b;
                }
            }
        }
    }
}

// ---------------- epilogue: batch is SORTED -> segmented mean ----------------
__global__ void bounds_k(const int* __restrict__ batch, int* __restrict__ bounds) {
    int g = threadIdx.x;
    if (g > NG) return;
    int lo = 0, hi = NN;
    while (lo < hi) {
        int mid = (lo + hi) >> 1;
        if (batch[mid] < g) lo = mid + 1; else hi = mid;
    }
    bounds[g] = lo;
}

__global__ __launch_bounds__(128) void finalize2_k(const unsigned short* __restrict__ aggy,
                                                   const unsigned short* __restrict__ rr,
                                                   const float* __restrict__ b3,
                                                   const int* __restrict__ batch,
                                                   float* __restrict__ outsum) {
    const int CH = 25;                        // 2000 * 25 = 50000
    int n0 = blockIdx.x * CH;
    int c = threadIdx.x;
    float bias = b3[c];
    int g = batch[n0];
    float acc = 0.f;
    for (int i = 0; i < CH; ++i) {
        int n = n0 + i;
        int gn = batch[n];
        if (gn != g) {
            unsafeAtomicAdd(&outsum[(size_t)g * 128 + c], acc);
            acc = 0.f; g = gn;
        }
        size_t idx = (size_t)n * 128 + c;
        float v = __uint_as_float((unsigned int)aggy[idx] << 16)
                + __uint_as_float((unsigned int)rr[idx] << 16) + bias;
        v = v > 0.f ? v : (__expf(v) - 1.f);
        acc += v;
    }
    unsafeAtomicAdd(&outsum[(size_t)g * 128 + c], acc);
}

__global__ void divide_k(const int* __restrict__ bounds, float* __restrict__ out) {
    int i = blockIdx.x * 256 + threadIdx.x;
    if (i < NG * 128) {
        int g = i >> 7;
        float c = (float)(bounds[g + 1] - bounds[g]);
        out[i] /= fmaxf(c, 1.f);
    }
}

extern "C" void kernel_launch(void* const* d_in, const int* in_sizes, int n_in,
                              void* d_out, int out_size, void* d_ws, size_t ws_size,
                              hipStream_t stream) {
    const float* x       = (const float*)d_in[0];
    const int*   ei      = (const int*)d_in[1];
    const int*   batch   = (const int*)d_in[2];
    const float* w_rel1  = (const float*)d_in[3];
    const float* b_rel1  = (const float*)d_in[4];
    const float* w_root1 = (const float*)d_in[5];
    const float* w_rel2  = (const float*)d_in[6];
    const float* b_rel2  = (const float*)d_in[7];
    const float* w_root2 = (const float*)d_in[8];
    const float* w_rel3  = (const float*)d_in[9];
    const float* b_rel3  = (const float*)d_in[10];
    const float* w_root3 = (const float*)d_in[11];
    const int* esrc = ei;
    const int* edst = ei + NE;

    // workspace: bf16 feature buffers then int arrays
    unsigned short* Ab = (unsigned short*)d_ws;          // [NN,128] agg out / y
    unsigned short* Bb = Ab + (size_t)NN * 128;          // [NN,128] h1 / r
    unsigned short* Cb = Bb + (size_t)NN * 128;          // [NN,256] h2 ; front = agg(y)
    unsigned short* xb = Cb + (size_t)NN * 256;          // [NN,128] x in bf16
    int* rowptr = (int*)(xb + (size_t)NN * 128);         // NN+1
    int* colsrc = rowptr + (NN + 1);                     // NE
    int* tmp    = colsrc + NE;                           // NE
    int* H      = tmp + NE;                              // NBK*NBK
    int* S      = H + NBK * NBK;                         // NBK*NBK
    int* bounds = S + NBK * NBK;                         // NG+1
    float* outp = (float*)d_out;

    // --- CSR build (block-private counting sort; no global-atomic scatter) ---
    cvt_k<<<(NN * 32 + 255) / 256, 256, 0, stream>>>(x, xb);
    hist_k<<<NBK, 256, 0, stream>>>(edst, H);
    scanH_k<<<1, 1024, 0, stream>>>(H, S);
    scatter_k<<<NBK, 256, 0, stream>>>(esrc, edst, S, tmp);
    csr_k<<<NBK, 256, 0, stream>>>(tmp, S, rowptr, colsrc);

    dim3 g2(782, 2), g4(782, 4);

    // L1: h1 = elu([agg(x) | x] @ [w_rel1; w_root1] + b1)    -> Bb
    aggb_k<<<NN / 4, 256, 0, stream>>>(xb, rowptr, colsrc, Ab);
    gemm_k<128, 128, true, true, true, false><<<g2, 256, 0, stream>>>(Ab, xb, w_rel1, w_root1, b_rel1, Bb, nullptr);

    // L2: h2 = elu([agg(h1) | h1] @ [w_rel2; w_root2] + b2)  -> Cb
    aggb_k<<<NN / 4, 256, 0, stream>>>(Bb, rowptr, colsrc, Ab);
    gemm_k<128, 256, true, true, true, false><<<g4, 256, 0, stream>>>(Ab, Bb, w_rel2, w_root2, b_rel2, Cb, nullptr);

    // L3: y = h2@w_rel3 -> Ab, r = h2@w_root3 -> Bb (one dispatch); agg(y) -> Cb
    gemm_k<256, 256, false, false, false, true><<<g4, 256, 0, stream>>>(Cb, nullptr, w_rel3, w_root3, nullptr, Ab, Bb);
    aggb_k<<<NN / 4, 256, 0, stream>>>(Ab, rowptr, colsrc, Cb);

    // scatter_mean (batch sorted -> segmented reduction)
    hipMemsetAsync(outp, 0, NG * 128 * sizeof(float), stream);
    bounds_k<<<1, 128, 0, stream>>>(batch, bounds);
    finalize2_k<<<NN / 25, 128, 0, stream>>>(Cb, Bb, b_rel3, batch, outp);
    divide_k<<<(NG * 128 + 255) / 256, 256, 0, stream>>>(bounds, outp);
}

// Round 6
// 361.866 us; speedup vs baseline: 2.2000x; 1.1521x over previous
//
#include <hip/hip_runtime.h>
#include <math.h>

#define NN 50000
#define NE 800000
#define NG 64
#define NBK 196          // buckets of 256 nodes: ceil(50000/256)
#define ECH 4082         // edges per hist/scatter block: 196*4082 >= 800000
#define TOTH (NBK * NBK) // 38416
#define NBH 151          // ceil(TOTH/256)

typedef __attribute__((ext_vector_type(8))) __bf16 bf16x8;
typedef __attribute__((ext_vector_type(8))) short short8;
typedef __attribute__((ext_vector_type(4))) float f32x4;

__device__ inline unsigned short f2bf(float f) {
    unsigned int u = __float_as_uint(f);
    u += 0x7fffu + ((u >> 16) & 1u);   // round-to-nearest-even
    return (unsigned short)(u >> 16);
}
__device__ inline float bflo(unsigned int v) { return __uint_as_float(v << 16); }
__device__ inline float bfhi(unsigned int v) { return __uint_as_float(v & 0xffff0000u); }

// ---------------- fp32 -> bf16 convert (x only) ----------------
__global__ __launch_bounds__(256) void cvt_k(const float* __restrict__ in,
                                             unsigned short* __restrict__ outp) {
    int i = blockIdx.x * 256 + threadIdx.x;      // 4 elems per thread
    if (i < NN * 32) {
        float4 v = ((const float4*)in)[i];
        unsigned int p0 = ((unsigned int)f2bf(v.y) << 16) | f2bf(v.x);
        unsigned int p1 = ((unsigned int)f2bf(v.w) << 16) | f2bf(v.z);
        ((uint2*)outp)[i] = make_uint2(p0, p1);
    }
}

// ---------------- CSR build: block-private counting sort ----------------
// Phase 1: per-block bucket histogram. Block k handles edges [k*ECH,(k+1)*ECH).
__global__ __launch_bounds__(256) void hist_k(const int* __restrict__ dst,
                                              int* __restrict__ H) {
    __shared__ int h[NBK];
    int t = threadIdx.x, k = blockIdx.x;
    if (t < NBK) h[t] = 0;
    __syncthreads();
    int e0 = k * ECH, e1 = min(NE, e0 + ECH);
    for (int e = e0 + t; e < e1; e += 256) atomicAdd(&h[dst[e] >> 8], 1);
    __syncthreads();
    if (t < NBK) H[t * NBK + k] = h[t];          // bucket-major layout
}

// Phase 2 (hierarchical, parallel): exclusive scan of H (TOTH values) -> S
__global__ __launch_bounds__(256) void hsum_k(const int* __restrict__ H,
                                              int* __restrict__ hb) {
    int i = blockIdx.x * 256 + threadIdx.x;
    int v = (i < TOTH) ? H[i] : 0;
    for (int off = 32; off; off >>= 1) v += __shfl_xor(v, off, 64);
    __shared__ int ws[4];
    if ((threadIdx.x & 63) == 0) ws[threadIdx.x >> 6] = v;
    __syncthreads();
    if (threadIdx.x == 0) hb[blockIdx.x] = ws[0] + ws[1] + ws[2] + ws[3];
}

__global__ __launch_bounds__(256) void hscan_k(const int* __restrict__ hb,
                                               int* __restrict__ hoff) {
    __shared__ int s[256];
    int t = threadIdx.x;
    int v = (t < NBH) ? hb[t] : 0;
    s[t] = v; __syncthreads();
    for (int off = 1; off < 256; off <<= 1) {
        int u = (t >= off) ? s[t - off] : 0;
        __syncthreads(); s[t] += u; __syncthreads();
    }
    hoff[t] = (t == 0) ? 0 : s[t - 1];
}

__global__ __launch_bounds__(256) void happly_k(const int* __restrict__ H,
                                                const int* __restrict__ hoff,
                                                int* __restrict__ S) {
    int t = threadIdx.x;
    int i = blockIdx.x * 256 + t;
    int v = (i < TOTH) ? H[i] : 0;
    __shared__ int s[256];
    s[t] = v; __syncthreads();
    for (int off = 1; off < 256; off <<= 1) {
        int u = (t >= off) ? s[t - off] : 0;
        __syncthreads(); s[t] += u; __syncthreads();
    }
    if (i < TOTH) S[i] = hoff[blockIdx.x] + s[t] - v;
}

// Phase 3: scatter edges into bucket-major tmp using exclusive per-(bucket,block)
// slots -> privately-owned write regions (no cross-XCD line sharing).
// tmp entry packs (dst&255)<<16 | src   (src < 50000 < 2^16... packed low 16).
__global__ __launch_bounds__(256) void scatter_k(const int* __restrict__ src,
                                                 const int* __restrict__ dst,
                                                 const int* __restrict__ S,
                                                 int* __restrict__ tmp) {
    __shared__ int cur[NBK];
    int t = threadIdx.x, k = blockIdx.x;
    if (t < NBK) cur[t] = S[t * NBK + k];
    __syncthreads();
    int e0 = k * ECH, e1 = min(NE, e0 + ECH);
    for (int e = e0 + t; e < e1; e += 256) {
        int d = dst[e];
        int p = atomicAdd(&cur[d >> 8], 1);
        tmp[p] = ((d & 255) << 16) | src[e];
    }
}

// Phase 4: per-bucket node-sort (bucket range ~16 KB, single-XCD L2 resident).
// Also emits rowptr.
__global__ __launch_bounds__(256) void csr_k(const int* __restrict__ tmp,
                                             const int* __restrict__ S,
                                             int* __restrict__ rowptr,
                                             int* __restrict__ colsrc) {
    __shared__ int hist[256], off[256], cur[256];
    int t = threadIdx.x, b = blockIdx.x;
    int base = S[b * NBK];
    int next = (b < NBK - 1) ? S[(b + 1) * NBK] : NE;
    int cntb = next - base;
    hist[t] = 0;
    __syncthreads();
    for (int i = t; i < cntb; i += 256) atomicAdd(&hist[tmp[base + i] >> 16], 1);
    __syncthreads();
    int v = hist[t];
    off[t] = v; __syncthreads();
    for (int o = 1; o < 256; o <<= 1) {                 // inclusive scan
        int u = (t >= o) ? off[t - o] : 0;
        __syncthreads(); off[t] += u; __syncthreads();
    }
    int excl = off[t] - v;                              // exclusive
    int node = b * 256 + t;
    if (node <= NN) rowptr[node] = base + excl;
    cur[t] = excl;
    __syncthreads();
    for (int i = t; i < cntb; i += 256) {
        int e = tmp[base + i];
        int p = atomicAdd(&cur[e >> 16], 1);
        colsrc[base + p] = e & 0xffff;
    }
}

// ---------------- edge aggregation, bf16 features (256 B/row) ----------------
__global__ __launch_bounds__(256) void aggb_k(const unsigned short* __restrict__ feat,
                                              const int* __restrict__ rowptr,
                                              const int* __restrict__ colsrc,
                                              unsigned short* __restrict__ outp) {
    int node = __builtin_amdgcn_readfirstlane((int)(blockIdx.x * 4 + (threadIdx.x >> 6)));
    int lane = threadIdx.x & 63;
    int beg = rowptr[node], end = rowptr[node + 1];
    float ax = 0.f, ay = 0.f;
    int e = beg;
    for (; e + 2 <= end; e += 2) {
        int s0 = colsrc[e], s1 = colsrc[e + 1];
        unsigned int v0 = *(const unsigned int*)&feat[(size_t)s0 * 128 + lane * 2];
        unsigned int v1 = *(const unsigned int*)&feat[(size_t)s1 * 128 + lane * 2];
        ax += bflo(v0); ay += bfhi(v0);
        ax += bflo(v1); ay += bfhi(v1);
    }
    if (e < end) {
        unsigned int v0 = *(const unsigned int*)&feat[(size_t)colsrc[e] * 128 + lane * 2];
        ax += bflo(v0); ay += bfhi(v0);
    }
    unsigned int p = ((unsigned int)f2bf(ay) << 16) | f2bf(ax);
    *(unsigned int*)&outp[(size_t)node * 128 + lane * 2] = p;
}

// ---------------- fused GEMM via bf16 MFMA ----------------
template <int KA, int N, bool TWO, bool BIAS, bool ELU, bool SPLIT>
__global__ __launch_bounds__(256) void gemm_k(const unsigned short* __restrict__ A1,
                                              const unsigned short* __restrict__ A2,
                                              const float* __restrict__ W1,
                                              const float* __restrict__ W2,
                                              const float* __restrict__ bias,
                                              unsigned short* __restrict__ Cout,
                                              unsigned short* __restrict__ Cout2) {
    constexpr int KTOT = TWO ? 2 * KA : KA;
    __shared__ __attribute__((aligned(16))) unsigned short As[64][40];
    __shared__ __attribute__((aligned(16))) unsigned short Bs[64][40];
    const int t = threadIdx.x;
    const int m0 = blockIdx.x * 64;
    const int n0 = blockIdx.y * 64;
    const int wv = t >> 6, lane = t & 63, qd = lane >> 4, l16 = lane & 15;
    f32x4 acc[4] = {};

    const int arow = t >> 2;
    const int akk  = (t & 3) << 3;
    const int wkl  = t >> 3;
    const int wng  = (t & 7) << 3;
    const int gm = m0 + arow;

    for (int k0 = 0; k0 < KTOT; k0 += 32) {
        {   // stage A tile 64x32 (bf16 direct, 16 B per thread)
            int kabs = k0 + akk;
            const unsigned short* src = (TWO && kabs >= KA)
                ? (A2 + (size_t)gm * KA + (kabs - KA))
                : (A1 + (size_t)gm * KA + kabs);
            short8 sv = {};
            if (gm < NN) sv = *(const short8*)src;
            *(short8*)&As[arow][akk] = sv;
        }
        {   // stage W tile 32x64 (fp32 -> bf16), transposed into Bs[n][k]
            int kabs = k0 + wkl;
            const float* src;
            if (SPLIT) {
                const float* wsel = (n0 < 128) ? W1 : W2;
                src = wsel + (size_t)kabs * 128 + ((n0 + wng) & 127);
            } else if (TWO && kabs >= KA) {
                src = W2 + (size_t)(kabs - KA) * N + n0 + wng;
            } else {
                src = W1 + (size_t)kabs * N + n0 + wng;
            }
            float4 v0 = *(const float4*)src;
            float4 v1 = *(const float4*)(src + 4);
            Bs[wng + 0][wkl] = f2bf(v0.x); Bs[wng + 1][wkl] = f2bf(v0.y);
            Bs[wng + 2][wkl] = f2bf(v0.z); Bs[wng + 3][wkl] = f2bf(v0.w);
            Bs[wng + 4][wkl] = f2bf(v1.x); Bs[wng + 5][wkl] = f2bf(v1.y);
            Bs[wng + 6][wkl] = f2bf(v1.z); Bs[wng + 7][wkl] = f2bf(v1.w);
        }
        __syncthreads();
        bf16x8 af = *(const bf16x8*)&As[wv * 16 + l16][qd * 8];
#pragma unroll
        for (int j = 0; j < 4; ++j) {
            bf16x8 bfv = *(const bf16x8*)&Bs[j * 16 + l16][qd * 8];
            acc[j] = __builtin_amdgcn_mfma_f32_16x16x32_bf16(af, bfv, acc[j], 0, 0, 0);
        }
        __syncthreads();
    }
#pragma unroll
    for (int j = 0; j < 4; ++j) {
#pragma unroll
        for (int r = 0; r < 4; ++r) {
            int mm = m0 + wv * 16 + qd * 4 + r;
            if (mm < NN) {
                int nn = n0 + j * 16 + l16;
                float v = acc[j][r];
                if (BIAS) v += bias[nn];
                if (ELU) v = v > 0.f ? v : (__expf(v) - 1.f);
                unsigned short b = f2bf(v);
                if (SPLIT) {
                    unsigned short* dst = (nn < 128) ? Cout : Cout2;
                    dst[(size_t)mm * 128 + (nn & 127)] = b;
                } else {
                    Cout[(size_t)mm * N + nn] = b;
                }
            }
        }
    }
}

// ---------------- epilogue: batch is SORTED -> segmented mean ----------------
__global__ void bounds_k(const int* __restrict__ batch, int* __restrict__ bounds) {
    int g = threadIdx.x;
    if (g > NG) return;
    int lo = 0, hi = NN;
    while (lo < hi) {
        int mid = (lo + hi) >> 1;
        if (batch[mid] < g) lo = mid + 1; else hi = mid;
    }
    bounds[g] = lo;
}

__global__ __launch_bounds__(128) void finalize2_k(const unsigned short* __restrict__ aggy,
                                                   const unsigned short* __restrict__ rr,
                                                   const float* __restrict__ b3,
                                                   const int* __restrict__ batch,
                                                   float* __restrict__ outsum) {
    const int CH = 25;                        // 2000 * 25 = 50000
    int n0 = blockIdx.x * CH;
    int c = threadIdx.x;
    float bias = b3[c];
    int g = batch[n0];
    float acc = 0.f;
    for (int i = 0; i < CH; ++i) {
        int n = n0 + i;
        int gn = batch[n];
        if (gn != g) {
            unsafeAtomicAdd(&outsum[(size_t)g * 128 + c], acc);
            acc = 0.f; g = gn;
        }
        size_t idx = (size_t)n * 128 + c;
        float v = __uint_as_float((unsigned int)aggy[idx] << 16)
                + __uint_as_float((unsigned int)rr[idx] << 16) + bias;
        v = v > 0.f ? v : (__expf(v) - 1.f);
        acc += v;
    }
    unsafeAtomicAdd(&outsum[(size_t)g * 128 + c], acc);
}

__global__ void divide_k(const int* __restrict__ bounds, float* __restrict__ out) {
    int i = blockIdx.x * 256 + threadIdx.x;
    if (i < NG * 128) {
        int g = i >> 7;
        float c = (float)(bounds[g + 1] - bounds[g]);
        out[i] /= fmaxf(c, 1.f);
    }
}

extern "C" void kernel_launch(void* const* d_in, const int* in_sizes, int n_in,
                              void* d_out, int out_size, void* d_ws, size_t ws_size,
                              hipStream_t stream) {
    const float* x       = (const float*)d_in[0];
    const int*   ei      = (const int*)d_in[1];
    const int*   batch   = (const int*)d_in[2];
    const float* w_rel1  = (const float*)d_in[3];
    const float* b_rel1  = (const float*)d_in[4];
    const float* w_root1 = (const float*)d_in[5];
    const float* w_rel2  = (const float*)d_in[6];
    const float* b_rel2  = (const float*)d_in[7];
    const float* w_root2 = (const float*)d_in[8];
    const float* w_rel3  = (const float*)d_in[9];
    const float* b_rel3  = (const float*)d_in[10];
    const float* w_root3 = (const float*)d_in[11];
    const int* esrc = ei;
    const int* edst = ei + NE;

    // workspace: bf16 feature buffers then int arrays
    unsigned short* Ab = (unsigned short*)d_ws;          // [NN,128] agg out / y
    unsigned short* Bb = Ab + (size_t)NN * 128;          // [NN,128] h1 / r
    unsigned short* Cb = Bb + (size_t)NN * 128;          // [NN,256] h2 ; front = agg(y)
    unsigned short* xb = Cb + (size_t)NN * 256;          // [NN,128] x in bf16
    int* rowptr = (int*)(xb + (size_t)NN * 128);         // NN+1
    int* colsrc = rowptr + (NN + 1);                     // NE
    int* tmp    = colsrc + NE;                           // NE
    int* H      = tmp + NE;                              // TOTH
    int* S      = H + TOTH;                              // TOTH
    int* hb     = S + TOTH;                              // 256
    int* hoff   = hb + 256;                              // 256
    int* bounds = hoff + 256;                            // NG+1
    float* outp = (float*)d_out;

    // --- CSR build (block-private counting sort; hierarchical parallel scan) ---
    cvt_k<<<(NN * 32 + 255) / 256, 256, 0, stream>>>(x, xb);
    hist_k<<<NBK, 256, 0, stream>>>(edst, H);
    hsum_k<<<NBH, 256, 0, stream>>>(H, hb);
    hscan_k<<<1, 256, 0, stream>>>(hb, hoff);
    happly_k<<<NBH, 256, 0, stream>>>(H, hoff, S);
    scatter_k<<<NBK, 256, 0, stream>>>(esrc, edst, S, tmp);
    csr_k<<<NBK, 256, 0, stream>>>(tmp, S, rowptr, colsrc);

    dim3 g2(782, 2), g4(782, 4);

    // L1: h1 = elu([agg(x) | x] @ [w_rel1; w_root1] + b1)    -> Bb
    aggb_k<<<NN / 4, 256, 0, stream>>>(xb, rowptr, colsrc, Ab);
    gemm_k<128, 128, true, true, true, false><<<g2, 256, 0, stream>>>(Ab, xb, w_rel1, w_root1, b_rel1, Bb, nullptr);

    // L2: h2 = elu([agg(h1) | h1] @ [w_rel2; w_root2] + b2)  -> Cb
    aggb_k<<<NN / 4, 256, 0, stream>>>(Bb, rowptr, colsrc, Ab);
    gemm_k<128, 256, true, true, true, false><<<g4, 256, 0, stream>>>(Ab, Bb, w_rel2, w_root2, b_rel2, Cb, nullptr);

    // L3: y = h2@w_rel3 -> Ab, r = h2@w_root3 -> Bb (one dispatch); agg(y) -> Cb
    gemm_k<256, 256, false, false, false, true><<<g4, 256, 0, stream>>>(Cb, nullptr, w_rel3, w_root3, nullptr, Ab, Bb);
    aggb_k<<<NN / 4, 256, 0, stream>>>(Ab, rowptr, colsrc, Cb);

    // scatter_mean (batch sorted -> segmented reduction)
    hipMemsetAsync(outp, 0, NG * 128 * sizeof(float), stream);
    bounds_k<<<1, 128, 0, stream>>>(batch, bounds);
    finalize2_k<<<NN / 25, 128, 0, stream>>>(Cb, Bb, b_rel3, batch, outp);
    divide_k<<<(NG * 128 + 255) / 256, 256, 0, stream>>>(bounds, outp);
}

// Round 7
// 334.952 us; speedup vs baseline: 2.3768x; 1.0804x over previous
//
#include <hip/hip_runtime.h>
#include <math.h>

#define NN 50000
#define NNP 50048        // 391*128, padded row count for 128-tile GEMM staging
#define NE 800000
#define NG 64
#define NBK 196          // buckets of 256 nodes: ceil(50000/256)
#define ECH 4082         // edges per hist/scatter block: 196*4082 >= 800000
#define TOTH (NBK * NBK) // 38416
#define NBH 151          // ceil(TOTH/256)

typedef __attribute__((ext_vector_type(8))) __bf16 bf16x8;
typedef __attribute__((ext_vector_type(8))) short short8;
typedef __attribute__((ext_vector_type(4))) float f32x4;

__device__ inline unsigned short f2bf(float f) {
    unsigned int u = __float_as_uint(f);
    u += 0x7fffu + ((u >> 16) & 1u);   // round-to-nearest-even
    return (unsigned short)(u >> 16);
}
__device__ inline float bflo(unsigned int v) { return __uint_as_float(v << 16); }
__device__ inline float bfhi(unsigned int v) { return __uint_as_float(v & 0xffff0000u); }

#define GLD_LDS16(g, l)                                                          \
    __builtin_amdgcn_global_load_lds(                                            \
        (const __attribute__((address_space(1))) unsigned int*)(g),              \
        (__attribute__((address_space(3))) unsigned int*)(l), 16, 0, 0)

// ---------------- fp32 -> bf16 convert (x only) ----------------
__global__ __launch_bounds__(256) void cvt_k(const float* __restrict__ in,
                                             unsigned short* __restrict__ outp) {
    int i = blockIdx.x * 256 + threadIdx.x;      // 4 elems per thread
    if (i < NN * 32) {
        float4 v = ((const float4*)in)[i];
        unsigned int p0 = ((unsigned int)f2bf(v.y) << 16) | f2bf(v.x);
        unsigned int p1 = ((unsigned int)f2bf(v.w) << 16) | f2bf(v.z);
        ((uint2*)outp)[i] = make_uint2(p0, p1);
    }
}

// ---------------- weight pre-transpose to bf16 [n][k] ----------------
// W1T [128n][256k]: k<128 w_rel1^T else w_root1^T   (L1: A=[agg(x)|x])
// W2T [256n][256k]: k<128 w_rel2^T else w_root2^T   (L2: A=[agg(h1)|h1])
// W3T [256n][256k]: n<128 w_rel3^T else w_root3^T   (L3: split outputs y|r)
__global__ __launch_bounds__(256) void wt_k(const float* __restrict__ wr1,
                                            const float* __restrict__ wo1,
                                            const float* __restrict__ wr2,
                                            const float* __restrict__ wo2,
                                            const float* __restrict__ wr3,
                                            const float* __restrict__ wo3,
                                            unsigned short* __restrict__ W1T,
                                            unsigned short* __restrict__ W2T,
                                            unsigned short* __restrict__ W3T) {
    int id = blockIdx.x * 256 + threadIdx.x;
    if (id < 32768) {
        int n = id >> 8, k = id & 255;
        float v = (k < 128) ? wr1[k * 128 + n] : wo1[(k - 128) * 128 + n];
        W1T[id] = f2bf(v);
    } else if (id < 98304) {
        int j = id - 32768; int n = j >> 8, k = j & 255;
        float v = (k < 128) ? wr2[k * 256 + n] : wo2[(k - 128) * 256 + n];
        W2T[j] = f2bf(v);
    } else if (id < 163840) {
        int j = id - 98304; int n = j >> 8, k = j & 255;
        float v = (n < 128) ? wr3[k * 128 + n] : wo3[k * 128 + (n - 128)];
        W3T[j] = f2bf(v);
    }
}

// ---------------- CSR build: block-private counting sort ----------------
__global__ __launch_bounds__(256) void hist_k(const int* __restrict__ dst,
                                              int* __restrict__ H) {
    __shared__ int h[NBK];
    int t = threadIdx.x, k = blockIdx.x;
    if (t < NBK) h[t] = 0;
    __syncthreads();
    int e0 = k * ECH, e1 = min(NE, e0 + ECH);
    for (int e = e0 + t; e < e1; e += 256) atomicAdd(&h[dst[e] >> 8], 1);
    __syncthreads();
    if (t < NBK) H[t * NBK + k] = h[t];          // bucket-major layout
}

__global__ __launch_bounds__(256) void hsum_k(const int* __restrict__ H,
                                              int* __restrict__ hb) {
    int i = blockIdx.x * 256 + threadIdx.x;
    int v = (i < TOTH) ? H[i] : 0;
    for (int off = 32; off; off >>= 1) v += __shfl_xor(v, off, 64);
    __shared__ int ws[4];
    if ((threadIdx.x & 63) == 0) ws[threadIdx.x >> 6] = v;
    __syncthreads();
    if (threadIdx.x == 0) hb[blockIdx.x] = ws[0] + ws[1] + ws[2] + ws[3];
}

__global__ __launch_bounds__(256) void hscan_k(const int* __restrict__ hb,
                                               int* __restrict__ hoff) {
    __shared__ int s[256];
    int t = threadIdx.x;
    int v = (t < NBH) ? hb[t] : 0;
    s[t] = v; __syncthreads();
    for (int off = 1; off < 256; off <<= 1) {
        int u = (t >= off) ? s[t - off] : 0;
        __syncthreads(); s[t] += u; __syncthreads();
    }
    hoff[t] = (t == 0) ? 0 : s[t - 1];
}

__global__ __launch_bounds__(256) void happly_k(const int* __restrict__ H,
                                                const int* __restrict__ hoff,
                                                int* __restrict__ S) {
    int t = threadIdx.x;
    int i = blockIdx.x * 256 + t;
    int v = (i < TOTH) ? H[i] : 0;
    __shared__ int s[256];
    s[t] = v; __syncthreads();
    for (int off = 1; off < 256; off <<= 1) {
        int u = (t >= off) ? s[t - off] : 0;
        __syncthreads(); s[t] += u; __syncthreads();
    }
    if (i < TOTH) S[i] = hoff[blockIdx.x] + s[t] - v;
}

__global__ __launch_bounds__(256) void scatter_k(const int* __restrict__ src,
                                                 const int* __restrict__ dst,
                                                 const int* __restrict__ S,
                                                 int* __restrict__ tmp) {
    __shared__ int cur[NBK];
    int t = threadIdx.x, k = blockIdx.x;
    if (t < NBK) cur[t] = S[t * NBK + k];
    __syncthreads();
    int e0 = k * ECH, e1 = min(NE, e0 + ECH);
    for (int e = e0 + t; e < e1; e += 256) {
        int d = dst[e];
        int p = atomicAdd(&cur[d >> 8], 1);
        tmp[p] = ((d & 255) << 16) | src[e];
    }
}

__global__ __launch_bounds__(256) void csr_k(const int* __restrict__ tmp,
                                             const int* __restrict__ S,
                                             int* __restrict__ rowptr,
                                             int* __restrict__ colsrc) {
    __shared__ int hist[256], off[256], cur[256];
    int t = threadIdx.x, b = blockIdx.x;
    int base = S[b * NBK];
    int next = (b < NBK - 1) ? S[(b + 1) * NBK] : NE;
    int cntb = next - base;
    hist[t] = 0;
    __syncthreads();
    for (int i = t; i < cntb; i += 256) atomicAdd(&hist[tmp[base + i] >> 16], 1);
    __syncthreads();
    int v = hist[t];
    off[t] = v; __syncthreads();
    for (int o = 1; o < 256; o <<= 1) {
        int u = (t >= o) ? off[t - o] : 0;
        __syncthreads(); off[t] += u; __syncthreads();
    }
    int excl = off[t] - v;
    int node = b * 256 + t;
    if (node <= NN) rowptr[node] = base + excl;
    cur[t] = excl;
    __syncthreads();
    for (int i = t; i < cntb; i += 256) {
        int e = tmp[base + i];
        int p = atomicAdd(&cur[e >> 16], 1);
        colsrc[base + p] = e & 0xffff;
    }
}

// ---------------- edge aggregation, bf16 features (256 B/row) ----------------
__global__ __launch_bounds__(256) void aggb_k(const unsigned short* __restrict__ feat,
                                              const int* __restrict__ rowptr,
                                              const int* __restrict__ colsrc,
                                              unsigned short* __restrict__ outp) {
    int node = __builtin_amdgcn_readfirstlane((int)(blockIdx.x * 4 + (threadIdx.x >> 6)));
    int lane = threadIdx.x & 63;
    int beg = rowptr[node], end = rowptr[node + 1];
    float ax = 0.f, ay = 0.f;
    int e = beg;
    for (; e + 2 <= end; e += 2) {
        int s0 = colsrc[e], s1 = colsrc[e + 1];
        unsigned int v0 = *(const unsigned int*)&feat[(size_t)s0 * 128 + lane * 2];
        unsigned int v1 = *(const unsigned int*)&feat[(size_t)s1 * 128 + lane * 2];
        ax += bflo(v0); ay += bfhi(v0);
        ax += bflo(v1); ay += bfhi(v1);
    }
    if (e < end) {
        unsigned int v0 = *(const unsigned int*)&feat[(size_t)colsrc[e] * 128 + lane * 2];
        ax += bflo(v0); ay += bfhi(v0);
    }
    unsigned int p = ((unsigned int)f2bf(ay) << 16) | f2bf(ax);
    *(unsigned int*)&outp[(size_t)node * 128 + lane * 2] = p;
}

// ---------------- 128x128-tile MFMA GEMM (m97 structure) ----------------
// A: [NNP,KA] bf16 row-major (TWO: virtual [A1|A2], KTOT=2*KA).
// WT: [N][KTOT] bf16 (pre-transposed). Staging via global_load_lds width-16.
// SPLIT: cols 0..127 -> Cout, 128..255 -> Cout2 (each row-stride 128).
template <int KA, int N, bool TWO, bool BIAS, bool ELU, bool SPLIT>
__global__ __launch_bounds__(256) void gemm_k(const unsigned short* __restrict__ A1,
                                              const unsigned short* __restrict__ A2,
                                              const unsigned short* __restrict__ WT,
                                              const float* __restrict__ bias,
                                              unsigned short* __restrict__ Cout,
                                              unsigned short* __restrict__ Cout2) {
    constexpr int KTOT = TWO ? 2 * KA : KA;
    __shared__ __attribute__((aligned(16))) unsigned short As[128 * 32];  // [m][k]
    __shared__ __attribute__((aligned(16))) unsigned short Bs[128 * 32];  // [n][k]
    const int t = threadIdx.x;
    const int wv = t >> 6, lane = t & 63;
    const int qd = lane >> 4, l16 = lane & 15;
    const int m0 = blockIdx.x * 128, n0 = blockIdx.y * 128;
    const int mh = (wv & 1) * 64, nh = (wv >> 1) * 64;
    const int srow = lane >> 2;            // row within 16-row chunk
    const int skk  = (lane & 3) * 8;       // k element offset within 32

    f32x4 acc[4][4] = {};

    for (int k0 = 0; k0 < KTOT; k0 += 32) {
        const unsigned short* Abase = (TWO && k0 >= KA) ? (A2 + (k0 - KA)) : (A1 + k0);
#pragma unroll
        for (int i = 0; i < 2; ++i) {
            int chunk = wv * 2 + i;        // 0..7, 16 rows each
            const unsigned short* g = Abase + (size_t)(m0 + chunk * 16 + srow) * KA + skk;
            GLD_LDS16(g, &As[chunk * 512]);
        }
        const unsigned short* Wbase = WT + k0;
#pragma unroll
        for (int i = 0; i < 2; ++i) {
            int chunk = wv * 2 + i;
            const unsigned short* g = Wbase + (size_t)(n0 + chunk * 16 + srow) * KTOT + skk;
            GLD_LDS16(g, &Bs[chunk * 512]);
        }
        __syncthreads();
        bf16x8 af[4], bfr[4];
#pragma unroll
        for (int mi = 0; mi < 4; ++mi)
            af[mi] = *(const bf16x8*)&As[(mh + mi * 16 + l16) * 32 + qd * 8];
#pragma unroll
        for (int ni = 0; ni < 4; ++ni)
            bfr[ni] = *(const bf16x8*)&Bs[(nh + ni * 16 + l16) * 32 + qd * 8];
#pragma unroll
        for (int mi = 0; mi < 4; ++mi)
#pragma unroll
            for (int ni = 0; ni < 4; ++ni)
                acc[mi][ni] = __builtin_amdgcn_mfma_f32_16x16x32_bf16(
                    af[mi], bfr[ni], acc[mi][ni], 0, 0, 0);
        __syncthreads();
    }

#pragma unroll
    for (int mi = 0; mi < 4; ++mi) {
#pragma unroll
        for (int ni = 0; ni < 4; ++ni) {
#pragma unroll
            for (int r = 0; r < 4; ++r) {
                int mm = m0 + mh + mi * 16 + qd * 4 + r;   // C/D: row = quad*4 + reg
                if (mm < NN) {
                    int nn = n0 + nh + ni * 16 + l16;      // col = lane&15
                    float v = acc[mi][ni][r];
                    if (BIAS) v += bias[nn];
                    if (ELU) v = v > 0.f ? v : (__expf(v) - 1.f);
                    unsigned short b = f2bf(v);
                    if (SPLIT) {
                        unsigned short* dst = (nn < 128) ? Cout : Cout2;
                        dst[(size_t)mm * 128 + (nn & 127)] = b;
                    } else {
                        Cout[(size_t)mm * N + nn] = b;
                    }
                }
            }
        }
    }
}

// ---------------- epilogue: batch is SORTED -> segmented mean ----------------
__global__ void bounds_k(const int* __restrict__ batch, int* __restrict__ bounds) {
    int g = threadIdx.x;
    if (g > NG) return;
    int lo = 0, hi = NN;
    while (lo < hi) {
        int mid = (lo + hi) >> 1;
        if (batch[mid] < g) lo = mid + 1; else hi = mid;
    }
    bounds[g] = lo;
}

__global__ __launch_bounds__(128) void finalize2_k(const unsigned short* __restrict__ aggy,
                                                   const unsigned short* __restrict__ rr,
                                                   const float* __restrict__ b3,
                                                   const int* __restrict__ batch,
                                                   float* __restrict__ outsum) {
    const int CH = 25;                        // 2000 * 25 = 50000
    int n0 = blockIdx.x * CH;
    int c = threadIdx.x;
    float bias = b3[c];
    int g = batch[n0];
    float acc = 0.f;
    for (int i = 0; i < CH; ++i) {
        int n = n0 + i;
        int gn = batch[n];
        if (gn != g) {
            unsafeAtomicAdd(&outsum[(size_t)g * 128 + c], acc);
            acc = 0.f; g = gn;
        }
        size_t idx = (size_t)n * 128 + c;
        float v = __uint_as_float((unsigned int)aggy[idx] << 16)
                + __uint_as_float((unsigned int)rr[idx] << 16) + bias;
        v = v > 0.f ? v : (__expf(v) - 1.f);
        acc += v;
    }
    unsafeAtomicAdd(&outsum[(size_t)g * 128 + c], acc);
}

__global__ void divide_k(const int* __restrict__ bounds, float* __restrict__ out) {
    int i = blockIdx.x * 256 + threadIdx.x;
    if (i < NG * 128) {
        int g = i >> 7;
        float c = (float)(bounds[g + 1] - bounds[g]);
        out[i] /= fmaxf(c, 1.f);
    }
}

extern "C" void kernel_launch(void* const* d_in, const int* in_sizes, int n_in,
                              void* d_out, int out_size, void* d_ws, size_t ws_size,
                              hipStream_t stream) {
    const float* x       = (const float*)d_in[0];
    const int*   ei      = (const int*)d_in[1];
    const int*   batch   = (const int*)d_in[2];
    const float* w_rel1  = (const float*)d_in[3];
    const float* b_rel1  = (const float*)d_in[4];
    const float* w_root1 = (const float*)d_in[5];
    const float* w_rel2  = (const float*)d_in[6];
    const float* b_rel2  = (const float*)d_in[7];
    const float* w_root2 = (const float*)d_in[8];
    const float* w_rel3  = (const float*)d_in[9];
    const float* b_rel3  = (const float*)d_in[10];
    const float* w_root3 = (const float*)d_in[11];
    const int* esrc = ei;
    const int* edst = ei + NE;

    // workspace: bf16 feature buffers (NNP-padded rows) then weights then ints
    unsigned short* Ab = (unsigned short*)d_ws;          // [NNP,128] agg out / y
    unsigned short* Bb = Ab + (size_t)NNP * 128;         // [NNP,128] h1 / r
    unsigned short* Cb = Bb + (size_t)NNP * 128;         // [NNP,256] h2 ; front = agg(y)
    unsigned short* xb = Cb + (size_t)NNP * 256;         // [NNP,128] x in bf16
    unsigned short* W1T = xb + (size_t)NNP * 128;        // [128,256]
    unsigned short* W2T = W1T + 128 * 256;               // [256,256]
    unsigned short* W3T = W2T + 256 * 256;               // [256,256]
    int* rowptr = (int*)(W3T + 256 * 256);               // NN+1
    int* colsrc = rowptr + (NN + 1);                     // NE
    int* tmp    = colsrc + NE;                           // NE
    int* H      = tmp + NE;                              // TOTH
    int* S      = H + TOTH;                              // TOTH
    int* hb     = S + TOTH;                              // 256
    int* hoff   = hb + 256;                              // 256
    int* bounds = hoff + 256;                            // NG+1
    float* outp = (float*)d_out;

    // --- setup: x->bf16, weight transposes, CSR build ---
    cvt_k<<<(NN * 32 + 255) / 256, 256, 0, stream>>>(x, xb);
    wt_k<<<640, 256, 0, stream>>>(w_rel1, w_root1, w_rel2, w_root2, w_rel3, w_root3,
                                  W1T, W2T, W3T);
    hist_k<<<NBK, 256, 0, stream>>>(edst, H);
    hsum_k<<<NBH, 256, 0, stream>>>(H, hb);
    hscan_k<<<1, 256, 0, stream>>>(hb, hoff);
    happly_k<<<NBH, 256, 0, stream>>>(H, hoff, S);
    scatter_k<<<NBK, 256, 0, stream>>>(esrc, edst, S, tmp);
    csr_k<<<NBK, 256, 0, stream>>>(tmp, S, rowptr, colsrc);

    dim3 g1(NNP / 128, 1), g2(NNP / 128, 2);

    // L1: h1 = elu([agg(x) | x] @ W1 + b1)    -> Bb
    aggb_k<<<NN / 4, 256, 0, stream>>>(xb, rowptr, colsrc, Ab);
    gemm_k<128, 128, true, true, true, false><<<g1, 256, 0, stream>>>(Ab, xb, W1T, b_rel1, Bb, nullptr);

    // L2: h2 = elu([agg(h1) | h1] @ W2 + b2)  -> Cb
    aggb_k<<<NN / 4, 256, 0, stream>>>(Bb, rowptr, colsrc, Ab);
    gemm_k<128, 256, true, true, true, false><<<g2, 256, 0, stream>>>(Ab, Bb, W2T, b_rel2, Cb, nullptr);

    // L3: y = h2@w_rel3 -> Ab, r = h2@w_root3 -> Bb (one dispatch); agg(y) -> Cb
    gemm_k<256, 256, false, false, false, true><<<g2, 256, 0, stream>>>(Cb, nullptr, W3T, nullptr, Ab, Bb);
    aggb_k<<<NN / 4, 256, 0, stream>>>(Ab, rowptr, colsrc, Cb);

    // scatter_mean (batch sorted -> segmented reduction)
    hipMemsetAsync(outp, 0, NG * 128 * sizeof(float), stream);
    bounds_k<<<1, 128, 0, stream>>>(batch, bounds);
    finalize2_k<<<NN / 25, 128, 0, stream>>>(Cb, Bb, b_rel3, batch, outp);
    divide_k<<<(NG * 128 + 255) / 256, 256, 0, stream>>>(bounds, outp);
}

// Round 8
// 322.146 us; speedup vs baseline: 2.4712x; 1.0398x over previous
//
#include <hip/hip_runtime.h>
#include <math.h>

#define NN 50000
#define NNP 50048        // 391*128, padded row count for GEMM staging
#define NE 800000
#define NG 64
#define NBK 196          // buckets of 256 nodes
#define ECH 4082         // edges per hist/scatter block
#define TOTH (NBK * NBK) // 38416
#define NBH 151          // ceil(TOTH/256)

typedef __attribute__((ext_vector_type(8))) __bf16 bf16x8;
typedef __attribute__((ext_vector_type(8))) short short8;
typedef __attribute__((ext_vector_type(4))) float f32x4;

__device__ inline unsigned short f2bf(float f) {
    unsigned int u = __float_as_uint(f);
    u += 0x7fffu + ((u >> 16) & 1u);   // round-to-nearest-even
    return (unsigned short)(u >> 16);
}
__device__ inline float bflo(unsigned int v) { return __uint_as_float(v << 16); }
__device__ inline float bfhi(unsigned int v) { return __uint_as_float(v & 0xffff0000u); }
__device__ inline float bfs(unsigned short v) { return __uint_as_float((unsigned int)v << 16); }

#define GLD_LDS16(g, l)                                                          \
    __builtin_amdgcn_global_load_lds(                                            \
        (const __attribute__((address_space(1))) unsigned int*)(g),              \
        (__attribute__((address_space(3))) unsigned int*)(l), 16, 0, 0)

// ---------------- setup: x fp32->bf16 + weight transposes (one launch) ----------------
__global__ __launch_bounds__(256) void setup_k(const float* __restrict__ x,
                                               const float* __restrict__ wr1,
                                               const float* __restrict__ wo1,
                                               const float* __restrict__ wr2,
                                               const float* __restrict__ wo2,
                                               const float* __restrict__ wr3,
                                               const float* __restrict__ wo3,
                                               unsigned short* __restrict__ xb,
                                               unsigned short* __restrict__ W1T,
                                               unsigned short* __restrict__ W2T,
                                               unsigned short* __restrict__ W3T) {
    int id = blockIdx.x * 256 + threadIdx.x;
    if (id < NN * 32) {                       // x: 4 floats per thread
        float4 v = ((const float4*)x)[id];
        unsigned int p0 = ((unsigned int)f2bf(v.y) << 16) | f2bf(v.x);
        unsigned int p1 = ((unsigned int)f2bf(v.w) << 16) | f2bf(v.z);
        ((uint2*)xb)[id] = make_uint2(p0, p1);
        return;
    }
    int w = id - NN * 32;
    if (w < 32768) {
        int n = w >> 8, k = w & 255;
        W1T[w] = f2bf((k < 128) ? wr1[k * 128 + n] : wo1[(k - 128) * 128 + n]);
    } else if (w < 98304) {
        int j = w - 32768; int n = j >> 8, k = j & 255;
        W2T[j] = f2bf((k < 128) ? wr2[k * 256 + n] : wo2[(k - 128) * 256 + n]);
    } else if (w < 163840) {
        int j = w - 98304; int n = j >> 8, k = j & 255;
        W3T[j] = f2bf((n < 128) ? wr3[k * 128 + n] : wo3[k * 128 + (n - 128)]);
    }
}

// ---------------- CSR build: block-private counting sort ----------------
__global__ __launch_bounds__(256) void hist_k(const int* __restrict__ dst,
                                              int* __restrict__ H) {
    __shared__ int h[NBK];
    int t = threadIdx.x, k = blockIdx.x;
    if (t < NBK) h[t] = 0;
    __syncthreads();
    int e0 = k * ECH, e1 = min(NE, e0 + ECH);
    for (int e = e0 + t; e < e1; e += 256) atomicAdd(&h[dst[e] >> 8], 1);
    __syncthreads();
    if (t < NBK) H[t * NBK + k] = h[t];          // bucket-major layout
}

__global__ __launch_bounds__(256) void hsum_k(const int* __restrict__ H,
                                              int* __restrict__ hb) {
    int i = blockIdx.x * 256 + threadIdx.x;
    int v = (i < TOTH) ? H[i] : 0;
    for (int off = 32; off; off >>= 1) v += __shfl_xor(v, off, 64);
    __shared__ int ws[4];
    if ((threadIdx.x & 63) == 0) ws[threadIdx.x >> 6] = v;
    __syncthreads();
    if (threadIdx.x == 0) hb[blockIdx.x] = ws[0] + ws[1] + ws[2] + ws[3];
}

__global__ __launch_bounds__(256) void hscan_k(const int* __restrict__ hb,
                                               int* __restrict__ hoff) {
    __shared__ int s[256];
    int t = threadIdx.x;
    int v = (t < NBH) ? hb[t] : 0;
    s[t] = v; __syncthreads();
    for (int off = 1; off < 256; off <<= 1) {
        int u = (t >= off) ? s[t - off] : 0;
        __syncthreads(); s[t] += u; __syncthreads();
    }
    hoff[t] = (t == 0) ? 0 : s[t - 1];
}

__global__ __launch_bounds__(256) void happly_k(const int* __restrict__ H,
                                                const int* __restrict__ hoff,
                                                int* __restrict__ S) {
    int t = threadIdx.x;
    int i = blockIdx.x * 256 + t;
    int v = (i < TOTH) ? H[i] : 0;
    __shared__ int s[256];
    s[t] = v; __syncthreads();
    for (int off = 1; off < 256; off <<= 1) {
        int u = (t >= off) ? s[t - off] : 0;
        __syncthreads(); s[t] += u; __syncthreads();
    }
    if (i < TOTH) S[i] = hoff[blockIdx.x] + s[t] - v;
}

__global__ __launch_bounds__(256) void scatter_k(const int* __restrict__ src,
                                                 const int* __restrict__ dst,
                                                 const int* __restrict__ S,
                                                 int* __restrict__ tmp) {
    __shared__ int cur[NBK];
    int t = threadIdx.x, k = blockIdx.x;
    if (t < NBK) cur[t] = S[t * NBK + k];
    __syncthreads();
    int e0 = k * ECH, e1 = min(NE, e0 + ECH);
    for (int e = e0 + t; e < e1; e += 256) {
        int d = dst[e];
        int p = atomicAdd(&cur[d >> 8], 1);
        tmp[p] = ((d & 255) << 16) | src[e];
    }
}

__global__ __launch_bounds__(256) void csr_k(const int* __restrict__ tmp,
                                             const int* __restrict__ S,
                                             int* __restrict__ rowptr,
                                             int* __restrict__ colsrc) {
    __shared__ int hist[256], off[256], cur[256];
    int t = threadIdx.x, b = blockIdx.x;
    int base = S[b * NBK];
    int next = (b < NBK - 1) ? S[(b + 1) * NBK] : NE;
    int cntb = next - base;
    hist[t] = 0;
    __syncthreads();
    for (int i = t; i < cntb; i += 256) atomicAdd(&hist[tmp[base + i] >> 16], 1);
    __syncthreads();
    int v = hist[t];
    off[t] = v; __syncthreads();
    for (int o = 1; o < 256; o <<= 1) {
        int u = (t >= o) ? off[t - o] : 0;
        __syncthreads(); off[t] += u; __syncthreads();
    }
    int excl = off[t] - v;
    int node = b * 256 + t;
    if (node <= NN) rowptr[node] = base + excl;
    cur[t] = excl;
    __syncthreads();
    for (int i = t; i < cntb; i += 256) {
        int e = tmp[base + i];
        int p = atomicAdd(&cur[e >> 16], 1);
        colsrc[base + p] = e & 0xffff;
    }
}

// ---------------- edge aggregation, bf16 features, 4-way MLP ----------------
__global__ __launch_bounds__(256) void aggb_k(const unsigned short* __restrict__ feat,
                                              const int* __restrict__ rowptr,
                                              const int* __restrict__ colsrc,
                                              unsigned short* __restrict__ outp) {
    int node = __builtin_amdgcn_readfirstlane((int)(blockIdx.x * 4 + (threadIdx.x >> 6)));
    int lane = threadIdx.x & 63;
    int beg = rowptr[node], end = rowptr[node + 1];
    float ax = 0.f, ay = 0.f;
    int e = beg;
    for (; e + 4 <= end; e += 4) {
        int s0 = colsrc[e], s1 = colsrc[e + 1], s2 = colsrc[e + 2], s3 = colsrc[e + 3];
        unsigned int v0 = *(const unsigned int*)&feat[(size_t)s0 * 128 + lane * 2];
        unsigned int v1 = *(const unsigned int*)&feat[(size_t)s1 * 128 + lane * 2];
        unsigned int v2 = *(const unsigned int*)&feat[(size_t)s2 * 128 + lane * 2];
        unsigned int v3 = *(const unsigned int*)&feat[(size_t)s3 * 128 + lane * 2];
        ax += bflo(v0); ay += bfhi(v0);
        ax += bflo(v1); ay += bfhi(v1);
        ax += bflo(v2); ay += bfhi(v2);
        ax += bflo(v3); ay += bfhi(v3);
    }
    for (; e < end; ++e) {
        unsigned int v0 = *(const unsigned int*)&feat[(size_t)colsrc[e] * 128 + lane * 2];
        ax += bflo(v0); ay += bfhi(v0);
    }
    unsigned int p = ((unsigned int)f2bf(ay) << 16) | f2bf(ax);
    *(unsigned int*)&outp[(size_t)node * 128 + lane * 2] = p;
}

// ---------------- tiled MFMA GEMM (m97 staging), MT x 128 tiles ----------------
// A: [NNP,KA] bf16 row-major (TWO: virtual [A1|A2], KTOT=2*KA).
// WT: [N][KTOT] bf16 pre-transposed. SPLIT: cols 0..127 -> Cout, 128.. -> Cout2.
template <int MT, int KA, int N, bool TWO, bool BIAS, bool ELU, bool SPLIT>
__global__ __launch_bounds__(256) void gemm_k(const unsigned short* __restrict__ A1,
                                              const unsigned short* __restrict__ A2,
                                              const unsigned short* __restrict__ WT,
                                              const float* __restrict__ bias,
                                              unsigned short* __restrict__ Cout,
                                              unsigned short* __restrict__ Cout2) {
    constexpr int KTOT = TWO ? 2 * KA : KA;
    constexpr int MI = MT / 32;                 // m-tiles per wave (2 or 4)
    __shared__ __attribute__((aligned(16))) unsigned short As[MT * 32];
    __shared__ __attribute__((aligned(16))) unsigned short Bs[128 * 32];
    const int t = threadIdx.x;
    const int wv = t >> 6, lane = t & 63;
    const int qd = lane >> 4, l16 = lane & 15;
    const int m0 = blockIdx.x * MT, n0 = blockIdx.y * 128;
    const int mh = (wv & 1) * (MT / 2), nh = (wv >> 1) * 64;
    const int srow = lane >> 2;            // row within 16-row chunk
    const int skk  = (lane & 3) * 8;       // k element offset within 32

    f32x4 acc[MI][4] = {};

    for (int k0 = 0; k0 < KTOT; k0 += 32) {
        const unsigned short* Abase = (TWO && k0 >= KA) ? (A2 + (k0 - KA)) : (A1 + k0);
#pragma unroll
        for (int i = 0; i < MT / 64; ++i) {
            int chunk = wv * (MT / 64) + i;        // 16 rows each
            const unsigned short* g = Abase + (size_t)(m0 + chunk * 16 + srow) * KA + skk;
            GLD_LDS16(g, &As[chunk * 512]);
        }
        const unsigned short* Wbase = WT + k0;
#pragma unroll
        for (int i = 0; i < 2; ++i) {
            int chunk = wv * 2 + i;
            const unsigned short* g = Wbase + (size_t)(n0 + chunk * 16 + srow) * KTOT + skk;
            GLD_LDS16(g, &Bs[chunk * 512]);
        }
        __syncthreads();
        bf16x8 af[MI], bfr[4];
#pragma unroll
        for (int mi = 0; mi < MI; ++mi)
            af[mi] = *(const bf16x8*)&As[(mh + mi * 16 + l16) * 32 + qd * 8];
#pragma unroll
        for (int ni = 0; ni < 4; ++ni)
            bfr[ni] = *(const bf16x8*)&Bs[(nh + ni * 16 + l16) * 32 + qd * 8];
#pragma unroll
        for (int mi = 0; mi < MI; ++mi)
#pragma unroll
            for (int ni = 0; ni < 4; ++ni)
                acc[mi][ni] = __builtin_amdgcn_mfma_f32_16x16x32_bf16(
                    af[mi], bfr[ni], acc[mi][ni], 0, 0, 0);
        __syncthreads();
    }

#pragma unroll
    for (int mi = 0; mi < MI; ++mi) {
#pragma unroll
        for (int ni = 0; ni < 4; ++ni) {
#pragma unroll
            for (int r = 0; r < 4; ++r) {
                int mm = m0 + mh + mi * 16 + qd * 4 + r;   // C/D: row = quad*4 + reg
                if (mm < NN) {
                    int nn = n0 + nh + ni * 16 + l16;      // col = lane&15
                    float v = acc[mi][ni][r];
                    if (BIAS) v += bias[nn];
                    if (ELU) v = v > 0.f ? v : (__expf(v) - 1.f);
                    unsigned short b = f2bf(v);
                    if (SPLIT) {
                        unsigned short* dst = (nn < 128) ? Cout : Cout2;
                        dst[(size_t)mm * 128 + (nn & 127)] = b;
                    } else {
                        Cout[(size_t)mm * N + nn] = b;
                    }
                }
            }
        }
    }
}

// ---------------- epilogue ----------------
// bounds + zero output accumulator (1 block).
__global__ __launch_bounds__(128) void bounds_k(const int* __restrict__ batch,
                                                int* __restrict__ bounds,
                                                float* __restrict__ outp) {
    int g = threadIdx.x;
    if (g <= NG) {
        int lo = 0, hi = NN;
        while (lo < hi) {
            int mid = (lo + hi) >> 1;
            if (batch[mid] < g) lo = mid + 1; else hi = mid;
        }
        bounds[g] = lo;
    }
    for (int i = threadIdx.x; i < NG * 128; i += 128) outp[i] = 0.f;
}

// fused: agg(y) per channel + r + b3, ELU, segmented graph-sum.
__global__ __launch_bounds__(128) void finalize3_k(const unsigned short* __restrict__ y,
                                                   const unsigned short* __restrict__ rr,
                                                   const float* __restrict__ b3,
                                                   const int* __restrict__ batch,
                                                   const int* __restrict__ rowptr,
                                                   const int* __restrict__ colsrc,
                                                   float* __restrict__ outsum) {
    const int CH = 10;                        // 5000 * 10 = 50000
    int n0 = blockIdx.x * CH;
    int c = threadIdx.x;
    float bias = b3[c];
    int g = batch[n0];
    float gacc = 0.f;
    for (int i = 0; i < CH; ++i) {
        int n = n0 + i;
        int gn = batch[n];
        if (gn != g) {
            unsafeAtomicAdd(&outsum[(size_t)g * 128 + c], gacc);
            gacc = 0.f; g = gn;
        }
        int beg = rowptr[n], end = rowptr[n + 1];
        float acc = 0.f;
        int e = beg;
        for (; e + 4 <= end; e += 4) {
            int s0 = colsrc[e], s1 = colsrc[e + 1], s2 = colsrc[e + 2], s3 = colsrc[e + 3];
            float v0 = bfs(y[(size_t)s0 * 128 + c]);
            float v1 = bfs(y[(size_t)s1 * 128 + c]);
            float v2 = bfs(y[(size_t)s2 * 128 + c]);
            float v3 = bfs(y[(size_t)s3 * 128 + c]);
            acc += v0 + v1 + v2 + v3;
        }
        for (; e < end; ++e) acc += bfs(y[(size_t)colsrc[e] * 128 + c]);
        float v = acc + bfs(rr[(size_t)n * 128 + c]) + bias;
        v = v > 0.f ? v : (__expf(v) - 1.f);
        gacc += v;
    }
    unsafeAtomicAdd(&outsum[(size_t)g * 128 + c], gacc);
}

__global__ void divide_k(const int* __restrict__ bounds, float* __restrict__ out) {
    int i = blockIdx.x * 256 + threadIdx.x;
    if (i < NG * 128) {
        int g = i >> 7;
        float c = (float)(bounds[g + 1] - bounds[g]);
        out[i] /= fmaxf(c, 1.f);
    }
}

extern "C" void kernel_launch(void* const* d_in, const int* in_sizes, int n_in,
                              void* d_out, int out_size, void* d_ws, size_t ws_size,
                              hipStream_t stream) {
    const float* x       = (const float*)d_in[0];
    const int*   ei      = (const int*)d_in[1];
    const int*   batch   = (const int*)d_in[2];
    const float* w_rel1  = (const float*)d_in[3];
    const float* b_rel1  = (const float*)d_in[4];
    const float* w_root1 = (const float*)d_in[5];
    const float* w_rel2  = (const float*)d_in[6];
    const float* b_rel2  = (const float*)d_in[7];
    const float* w_root2 = (const float*)d_in[8];
    const float* w_rel3  = (const float*)d_in[9];
    const float* b_rel3  = (const float*)d_in[10];
    const float* w_root3 = (const float*)d_in[11];
    const int* esrc = ei;
    const int* edst = ei + NE;

    unsigned short* Ab = (unsigned short*)d_ws;          // [NNP,128] agg out / y
    unsigned short* Bb = Ab + (size_t)NNP * 128;         // [NNP,128] h1 / r
    unsigned short* Cb = Bb + (size_t)NNP * 128;         // [NNP,256] h2
    unsigned short* xb = Cb + (size_t)NNP * 256;         // [NNP,128] x in bf16
    unsigned short* W1T = xb + (size_t)NNP * 128;        // [128,256]
    unsigned short* W2T = W1T + 128 * 256;               // [256,256]
    unsigned short* W3T = W2T + 256 * 256;               // [256,256]
    int* rowptr = (int*)(W3T + 256 * 256);               // NN+1
    int* colsrc = rowptr + (NN + 1);                     // NE
    int* tmp    = colsrc + NE;                           // NE
    int* H      = tmp + NE;                              // TOTH
    int* S      = H + TOTH;                              // TOTH
    int* hb     = S + TOTH;                              // 256
    int* hoff   = hb + 256;                              // 256
    int* bounds = hoff + 256;                            // NG+1
    float* outp = (float*)d_out;

    // --- setup (x->bf16 + weight transposes) and CSR build ---
    setup_k<<<(NN * 32 + 163840 + 255) / 256, 256, 0, stream>>>(
        x, w_rel1, w_root1, w_rel2, w_root2, w_rel3, w_root3, xb, W1T, W2T, W3T);
    hist_k<<<NBK, 256, 0, stream>>>(edst, H);
    hsum_k<<<NBH, 256, 0, stream>>>(H, hb);
    hscan_k<<<1, 256, 0, stream>>>(hb, hoff);
    happly_k<<<NBH, 256, 0, stream>>>(H, hoff, S);
    scatter_k<<<NBK, 256, 0, stream>>>(esrc, edst, S, tmp);
    csr_k<<<NBK, 256, 0, stream>>>(tmp, S, rowptr, colsrc);
    bounds_k<<<1, 128, 0, stream>>>(batch, bounds, outp);

    // L1: h1 = elu([agg(x) | x] @ W1 + b1)    -> Bb      (MT=64: 782 blocks)
    aggb_k<<<NN / 4, 256, 0, stream>>>(xb, rowptr, colsrc, Ab);
    gemm_k<64, 128, 128, true, true, true, false>
        <<<dim3(NNP / 64, 1), 256, 0, stream>>>(Ab, xb, W1T, b_rel1, Bb, nullptr);

    // L2: h2 = elu([agg(h1) | h1] @ W2 + b2)  -> Cb
    aggb_k<<<NN / 4, 256, 0, stream>>>(Bb, rowptr, colsrc, Ab);
    gemm_k<128, 128, 256, true, true, true, false>
        <<<dim3(NNP / 128, 2), 256, 0, stream>>>(Ab, Bb, W2T, b_rel2, Cb, nullptr);

    // L3: y = h2@w_rel3 -> Ab, r = h2@w_root3 -> Bb (one dispatch)
    gemm_k<128, 256, 256, false, false, false, true>
        <<<dim3(NNP / 128, 2), 256, 0, stream>>>(Cb, nullptr, W3T, nullptr, Ab, Bb);

    // fused agg(y)+elu+segmented mean numerator; then divide by counts
    finalize3_k<<<NN / 10, 128, 0, stream>>>(Ab, Bb, b_rel3, batch, rowptr, colsrc, outp);
    divide_k<<<(NG * 128 + 255) / 256, 256, 0, stream>>>(bounds, outp);
}

// Round 9
// 308.351 us; speedup vs baseline: 2.5818x; 1.0447x over previous
//
#include <hip/hip_runtime.h>
#include <math.h>

#define NN 50000
#define NNP 50048        // 391*128, padded row count for GEMM staging
#define NE 800000
#define NG 64
#define NBK 196          // buckets of 256 nodes
#define ECH 4082         // edges per hist/scatter block
#define TOTH (NBK * NBK) // 38416
#define NBH 151          // ceil(TOTH/256)

typedef __attribute__((ext_vector_type(8))) __bf16 bf16x8;
typedef __attribute__((ext_vector_type(8))) short short8;
typedef __attribute__((ext_vector_type(4))) float f32x4;

__device__ inline unsigned short f2bf(float f) {
    unsigned int u = __float_as_uint(f);
    u += 0x7fffu + ((u >> 16) & 1u);   // round-to-nearest-even
    return (unsigned short)(u >> 16);
}
__device__ inline float bflo(unsigned int v) { return __uint_as_float(v << 16); }
__device__ inline float bfhi(unsigned int v) { return __uint_as_float(v & 0xffff0000u); }
__device__ inline float bfs(unsigned short v) { return __uint_as_float((unsigned int)v << 16); }

#define GLD_LDS16(g, l)                                                          \
    __builtin_amdgcn_global_load_lds(                                            \
        (const __attribute__((address_space(1))) unsigned int*)(g),              \
        (__attribute__((address_space(3))) unsigned int*)(l), 16, 0, 0)

// ---------------- setup: x fp32->bf16 + weight transposes ----------------
__global__ __launch_bounds__(256) void setup_k(const float* __restrict__ x,
                                               const float* __restrict__ wr1,
                                               const float* __restrict__ wo1,
                                               const float* __restrict__ wr2,
                                               const float* __restrict__ wo2,
                                               const float* __restrict__ wr3,
                                               const float* __restrict__ wo3,
                                               unsigned short* __restrict__ xb,
                                               unsigned short* __restrict__ W1T,
                                               unsigned short* __restrict__ W2T,
                                               unsigned short* __restrict__ W3T) {
    int id = blockIdx.x * 256 + threadIdx.x;
    if (id < NN * 32) {                       // x: 4 floats per thread
        float4 v = ((const float4*)x)[id];
        unsigned int p0 = ((unsigned int)f2bf(v.y) << 16) | f2bf(v.x);
        unsigned int p1 = ((unsigned int)f2bf(v.w) << 16) | f2bf(v.z);
        ((uint2*)xb)[id] = make_uint2(p0, p1);
        return;
    }
    int w = id - NN * 32;
    if (w < 32768) {
        int n = w >> 8, k = w & 255;
        W1T[w] = f2bf((k < 128) ? wr1[k * 128 + n] : wo1[(k - 128) * 128 + n]);
    } else if (w < 98304) {
        int j = w - 32768; int n = j >> 8, k = j & 255;
        W2T[j] = f2bf((k < 128) ? wr2[k * 256 + n] : wo2[(k - 128) * 256 + n]);
    } else if (w < 163840) {
        int j = w - 98304; int n = j >> 8, k = j & 255;
        W3T[j] = f2bf((n < 128) ? wr3[k * 128 + n] : wo3[k * 128 + (n - 128)]);
    }
}

// ---------------- CSR build: block-private counting sort ----------------
__global__ __launch_bounds__(256) void hist_k(const int* __restrict__ dst,
                                              int* __restrict__ H) {
    __shared__ int h[NBK];
    int t = threadIdx.x, k = blockIdx.x;
    if (t < NBK) h[t] = 0;
    __syncthreads();
    int e0 = k * ECH, e1 = min(NE, e0 + ECH);
    for (int e = e0 + t; e < e1; e += 256) atomicAdd(&h[dst[e] >> 8], 1);
    __syncthreads();
    if (t < NBK) H[t * NBK + k] = h[t];          // bucket-major layout
}

__global__ __launch_bounds__(256) void hsum_k(const int* __restrict__ H,
                                              int* __restrict__ hb) {
    int i = blockIdx.x * 256 + threadIdx.x;
    int v = (i < TOTH) ? H[i] : 0;
    for (int off = 32; off; off >>= 1) v += __shfl_xor(v, off, 64);
    __shared__ int ws[4];
    if ((threadIdx.x & 63) == 0) ws[threadIdx.x >> 6] = v;
    __syncthreads();
    if (threadIdx.x == 0) hb[blockIdx.x] = ws[0] + ws[1] + ws[2] + ws[3];
}

__global__ __launch_bounds__(256) void hscan_k(const int* __restrict__ hb,
                                               int* __restrict__ hoff) {
    __shared__ int s[256];
    int t = threadIdx.x;
    int v = (t < NBH) ? hb[t] : 0;
    s[t] = v; __syncthreads();
    for (int off = 1; off < 256; off <<= 1) {
        int u = (t >= off) ? s[t - off] : 0;
        __syncthreads(); s[t] += u; __syncthreads();
    }
    hoff[t] = (t == 0) ? 0 : s[t - 1];
}

__global__ __launch_bounds__(256) void happly_k(const int* __restrict__ H,
                                                const int* __restrict__ hoff,
                                                int* __restrict__ S) {
    int t = threadIdx.x;
    int i = blockIdx.x * 256 + t;
    int v = (i < TOTH) ? H[i] : 0;
    __shared__ int s[256];
    s[t] = v; __syncthreads();
    for (int off = 1; off < 256; off <<= 1) {
        int u = (t >= off) ? s[t - off] : 0;
        __syncthreads(); s[t] += u; __syncthreads();
    }
    if (i < TOTH) S[i] = hoff[blockIdx.x] + s[t] - v;
}

__global__ __launch_bounds__(256) void scatter_k(const int* __restrict__ src,
                                                 const int* __restrict__ dst,
                                                 const int* __restrict__ S,
                                                 int* __restrict__ tmp) {
    __shared__ int cur[NBK];
    int t = threadIdx.x, k = blockIdx.x;
    if (t < NBK) cur[t] = S[t * NBK + k];
    __syncthreads();
    int e0 = k * ECH, e1 = min(NE, e0 + ECH);
    for (int e = e0 + t; e < e1; e += 256) {
        int d = dst[e];
        int p = atomicAdd(&cur[d >> 8], 1);
        tmp[p] = ((d & 255) << 16) | src[e];
    }
}

__global__ __launch_bounds__(256) void csr_k(const int* __restrict__ tmp,
                                             const int* __restrict__ S,
                                             int* __restrict__ rowptr,
                                             int* __restrict__ colsrc) {
    __shared__ int hist[256], off[256], cur[256];
    int t = threadIdx.x, b = blockIdx.x;
    int base = S[b * NBK];
    int next = (b < NBK - 1) ? S[(b + 1) * NBK] : NE;
    int cntb = next - base;
    hist[t] = 0;
    __syncthreads();
    for (int i = t; i < cntb; i += 256) atomicAdd(&hist[tmp[base + i] >> 16], 1);
    __syncthreads();
    int v = hist[t];
    off[t] = v; __syncthreads();
    for (int o = 1; o < 256; o <<= 1) {
        int u = (t >= o) ? off[t - o] : 0;
        __syncthreads(); off[t] += u; __syncthreads();
    }
    int excl = off[t] - v;
    int node = b * 256 + t;
    if (node <= NN) rowptr[node] = base + excl;
    cur[t] = excl;
    __syncthreads();
    for (int i = t; i < cntb; i += 256) {
        int e = tmp[base + i];
        int p = atomicAdd(&cur[e >> 16], 1);
        colsrc[base + p] = e & 0xffff;
    }
}

// ---------------- edge aggregation, bf16 features, 4-way MLP ----------------
__global__ __launch_bounds__(256) void aggb_k(const unsigned short* __restrict__ feat,
                                              const int* __restrict__ rowptr,
                                              const int* __restrict__ colsrc,
                                              unsigned short* __restrict__ outp) {
    int node = __builtin_amdgcn_readfirstlane((int)(blockIdx.x * 4 + (threadIdx.x >> 6)));
    int lane = threadIdx.x & 63;
    int beg = rowptr[node], end = rowptr[node + 1];
    float ax = 0.f, ay = 0.f;
    int e = beg;
    for (; e + 4 <= end; e += 4) {
        int s0 = colsrc[e], s1 = colsrc[e + 1], s2 = colsrc[e + 2], s3 = colsrc[e + 3];
        unsigned int v0 = *(const unsigned int*)&feat[(size_t)s0 * 128 + lane * 2];
        unsigned int v1 = *(const unsigned int*)&feat[(size_t)s1 * 128 + lane * 2];
        unsigned int v2 = *(const unsigned int*)&feat[(size_t)s2 * 128 + lane * 2];
        unsigned int v3 = *(const unsigned int*)&feat[(size_t)s3 * 128 + lane * 2];
        ax += bflo(v0); ay += bfhi(v0);
        ax += bflo(v1); ay += bfhi(v1);
        ax += bflo(v2); ay += bfhi(v2);
        ax += bflo(v3); ay += bfhi(v3);
    }
    for (; e < end; ++e) {
        unsigned int v0 = *(const unsigned int*)&feat[(size_t)colsrc[e] * 128 + lane * 2];
        ax += bflo(v0); ay += bfhi(v0);
    }
    unsigned int p = ((unsigned int)f2bf(ay) << 16) | f2bf(ax);
    *(unsigned int*)&outp[(size_t)node * 128 + lane * 2] = p;
}

// fused L3 epilogue: v = elu(agg(y)[n] + r[n] + b3), per-node bf16 (aggb structure)
__global__ __launch_bounds__(256) void aggf_k(const unsigned short* __restrict__ y,
                                              const unsigned short* __restrict__ rr,
                                              const float* __restrict__ b3,
                                              const int* __restrict__ rowptr,
                                              const int* __restrict__ colsrc,
                                              unsigned short* __restrict__ outp) {
    int node = __builtin_amdgcn_readfirstlane((int)(blockIdx.x * 4 + (threadIdx.x >> 6)));
    int lane = threadIdx.x & 63;
    int beg = rowptr[node], end = rowptr[node + 1];
    float ax = 0.f, ay = 0.f;
    int e = beg;
    for (; e + 4 <= end; e += 4) {
        int s0 = colsrc[e], s1 = colsrc[e + 1], s2 = colsrc[e + 2], s3 = colsrc[e + 3];
        unsigned int v0 = *(const unsigned int*)&y[(size_t)s0 * 128 + lane * 2];
        unsigned int v1 = *(const unsigned int*)&y[(size_t)s1 * 128 + lane * 2];
        unsigned int v2 = *(const unsigned int*)&y[(size_t)s2 * 128 + lane * 2];
        unsigned int v3 = *(const unsigned int*)&y[(size_t)s3 * 128 + lane * 2];
        ax += bflo(v0); ay += bfhi(v0);
        ax += bflo(v1); ay += bfhi(v1);
        ax += bflo(v2); ay += bfhi(v2);
        ax += bflo(v3); ay += bfhi(v3);
    }
    for (; e < end; ++e) {
        unsigned int v0 = *(const unsigned int*)&y[(size_t)colsrc[e] * 128 + lane * 2];
        ax += bflo(v0); ay += bfhi(v0);
    }
    unsigned int rv = *(const unsigned int*)&rr[(size_t)node * 128 + lane * 2];
    float2 bb = *(const float2*)&b3[lane * 2];
    float vx = ax + bflo(rv) + bb.x;
    float vy = ay + bfhi(rv) + bb.y;
    vx = vx > 0.f ? vx : (__expf(vx) - 1.f);
    vy = vy > 0.f ? vy : (__expf(vy) - 1.f);
    unsigned int p = ((unsigned int)f2bf(vy) << 16) | f2bf(vx);
    *(unsigned int*)&outp[(size_t)node * 128 + lane * 2] = p;
}

// ---------------- tiled MFMA GEMM (m97 staging), MT x 128 tiles ----------------
template <int MT, int KA, int N, bool TWO, bool BIAS, bool ELU, bool SPLIT>
__global__ __launch_bounds__(256) void gemm_k(const unsigned short* __restrict__ A1,
                                              const unsigned short* __restrict__ A2,
                                              const unsigned short* __restrict__ WT,
                                              const float* __restrict__ bias,
                                              unsigned short* __restrict__ Cout,
                                              unsigned short* __restrict__ Cout2) {
    constexpr int KTOT = TWO ? 2 * KA : KA;
    constexpr int MI = MT / 32;                 // m-tiles per wave
    __shared__ __attribute__((aligned(16))) unsigned short As[MT * 32];
    __shared__ __attribute__((aligned(16))) unsigned short Bs[128 * 32];
    const int t = threadIdx.x;
    const int wv = t >> 6, lane = t & 63;
    const int qd = lane >> 4, l16 = lane & 15;
    const int m0 = blockIdx.x * MT, n0 = blockIdx.y * 128;
    const int mh = (wv & 1) * (MT / 2), nh = (wv >> 1) * 64;
    const int srow = lane >> 2;
    const int skk  = (lane & 3) * 8;

    f32x4 acc[MI][4] = {};

    for (int k0 = 0; k0 < KTOT; k0 += 32) {
        const unsigned short* Abase = (TWO && k0 >= KA) ? (A2 + (k0 - KA)) : (A1 + k0);
#pragma unroll
        for (int i = 0; i < MT / 64; ++i) {
            int chunk = wv * (MT / 64) + i;
            const unsigned short* g = Abase + (size_t)(m0 + chunk * 16 + srow) * KA + skk;
            GLD_LDS16(g, &As[chunk * 512]);
        }
        const unsigned short* Wbase = WT + k0;
#pragma unroll
        for (int i = 0; i < 2; ++i) {
            int chunk = wv * 2 + i;
            const unsigned short* g = Wbase + (size_t)(n0 + chunk * 16 + srow) * KTOT + skk;
            GLD_LDS16(g, &Bs[chunk * 512]);
        }
        __syncthreads();
        bf16x8 af[MI], bfr[4];
#pragma unroll
        for (int mi = 0; mi < MI; ++mi)
            af[mi] = *(const bf16x8*)&As[(mh + mi * 16 + l16) * 32 + qd * 8];
#pragma unroll
        for (int ni = 0; ni < 4; ++ni)
            bfr[ni] = *(const bf16x8*)&Bs[(nh + ni * 16 + l16) * 32 + qd * 8];
#pragma unroll
        for (int mi = 0; mi < MI; ++mi)
#pragma unroll
            for (int ni = 0; ni < 4; ++ni)
                acc[mi][ni] = __builtin_amdgcn_mfma_f32_16x16x32_bf16(
                    af[mi], bfr[ni], acc[mi][ni], 0, 0, 0);
        __syncthreads();
    }

#pragma unroll
    for (int mi = 0; mi < MI; ++mi) {
#pragma unroll
        for (int ni = 0; ni < 4; ++ni) {
#pragma unroll
            for (int r = 0; r < 4; ++r) {
                int mm = m0 + mh + mi * 16 + qd * 4 + r;   // C/D: row = quad*4 + reg
                if (mm < NN) {
                    int nn = n0 + nh + ni * 16 + l16;      // col = lane&15
                    float v = acc[mi][ni][r];
                    if (BIAS) v += bias[nn];
                    if (ELU) v = v > 0.f ? v : (__expf(v) - 1.f);
                    unsigned short b = f2bf(v);
                    if (SPLIT) {
                        unsigned short* dst = (nn < 128) ? Cout : Cout2;
                        dst[(size_t)mm * 128 + (nn & 127)] = b;
                    } else {
                        Cout[(size_t)mm * N + nn] = b;
                    }
                }
            }
        }
    }
}

// ---------------- epilogue ----------------
__global__ __launch_bounds__(128) void bounds_k(const int* __restrict__ batch,
                                                int* __restrict__ bounds,
                                                float* __restrict__ outp) {
    int g = threadIdx.x;
    if (g <= NG) {
        int lo = 0, hi = NN;
        while (lo < hi) {
            int mid = (lo + hi) >> 1;
            if (batch[mid] < g) lo = mid + 1; else hi = mid;
        }
        bounds[g] = lo;
    }
    for (int i = threadIdx.x; i < NG * 128; i += 128) outp[i] = 0.f;
}

// segmented graph-sum of per-node bf16 values (batch sorted).
__global__ __launch_bounds__(128) void sum_k(const unsigned short* __restrict__ vals,
                                             const int* __restrict__ batch,
                                             float* __restrict__ outsum) {
    const int CH = 25;                        // 2000 * 25 = 50000
    int n0 = blockIdx.x * CH;
    int c = threadIdx.x;
    int g = batch[n0];
    float acc = 0.f;
    for (int i = 0; i < CH; ++i) {
        int n = n0 + i;
        int gn = batch[n];
        if (gn != g) {
            unsafeAtomicAdd(&outsum[(size_t)g * 128 + c], acc);
            acc = 0.f; g = gn;
        }
        acc += bfs(vals[(size_t)n * 128 + c]);
    }
    unsafeAtomicAdd(&outsum[(size_t)g * 128 + c], acc);
}

__global__ void divide_k(const int* __restrict__ bounds, float* __restrict__ out) {
    int i = blockIdx.x * 256 + threadIdx.x;
    if (i < NG * 128) {
        int g = i >> 7;
        float c = (float)(bounds[g + 1] - bounds[g]);
        out[i] /= fmaxf(c, 1.f);
    }
}

extern "C" void kernel_launch(void* const* d_in, const int* in_sizes, int n_in,
                              void* d_out, int out_size, void* d_ws, size_t ws_size,
                              hipStream_t stream) {
    const float* x       = (const float*)d_in[0];
    const int*   ei      = (const int*)d_in[1];
    const int*   batch   = (const int*)d_in[2];
    const float* w_rel1  = (const float*)d_in[3];
    const float* b_rel1  = (const float*)d_in[4];
    const float* w_root1 = (const float*)d_in[5];
    const float* w_rel2  = (const float*)d_in[6];
    const float* b_rel2  = (const float*)d_in[7];
    const float* w_root2 = (const float*)d_in[8];
    const float* w_rel3  = (const float*)d_in[9];
    const float* b_rel3  = (const float*)d_in[10];
    const float* w_root3 = (const float*)d_in[11];
    const int* esrc = ei;
    const int* edst = ei + NE;

    unsigned short* Ab = (unsigned short*)d_ws;          // [NNP,128] agg out / y
    unsigned short* Bb = Ab + (size_t)NNP * 128;         // [NNP,128] h1 / r
    unsigned short* Cb = Bb + (size_t)NNP * 128;         // [NNP,256] h2 ; front = node vals
    unsigned short* xb = Cb + (size_t)NNP * 256;         // [NNP,128] x in bf16
    unsigned short* W1T = xb + (size_t)NNP * 128;        // [128,256]
    unsigned short* W2T = W1T + 128 * 256;               // [256,256]
    unsigned short* W3T = W2T + 256 * 256;               // [256,256]
    int* rowptr = (int*)(W3T + 256 * 256);               // NN+1
    int* colsrc = rowptr + (NN + 1);                     // NE
    int* tmp    = colsrc + NE;                           // NE
    int* H      = tmp + NE;                              // TOTH
    int* S      = H + TOTH;                              // TOTH
    int* hb     = S + TOTH;                              // 256
    int* hoff   = hb + 256;                              // 256
    int* bounds = hoff + 256;                            // NG+1
    float* outp = (float*)d_out;

    // --- setup (x->bf16 + weight transposes) and CSR build ---
    setup_k<<<(NN * 32 + 163840 + 255) / 256, 256, 0, stream>>>(
        x, w_rel1, w_root1, w_rel2, w_root2, w_rel3, w_root3, xb, W1T, W2T, W3T);
    hist_k<<<NBK, 256, 0, stream>>>(edst, H);
    hsum_k<<<NBH, 256, 0, stream>>>(H, hb);
    hscan_k<<<1, 256, 0, stream>>>(hb, hoff);
    happly_k<<<NBH, 256, 0, stream>>>(H, hoff, S);
    scatter_k<<<NBK, 256, 0, stream>>>(esrc, edst, S, tmp);
    csr_k<<<NBK, 256, 0, stream>>>(tmp, S, rowptr, colsrc);
    bounds_k<<<1, 128, 0, stream>>>(batch, bounds, outp);

    // L1: h1 = elu([agg(x) | x] @ W1 + b1)    -> Bb      (MT=64: 782 blocks)
    aggb_k<<<NN / 4, 256, 0, stream>>>(xb, rowptr, colsrc, Ab);
    gemm_k<64, 128, 128, true, true, true, false>
        <<<dim3(NNP / 64, 1), 256, 0, stream>>>(Ab, xb, W1T, b_rel1, Bb, nullptr);

    // L2: h2 = elu([agg(h1) | h1] @ W2 + b2)  -> Cb
    aggb_k<<<NN / 4, 256, 0, stream>>>(Bb, rowptr, colsrc, Ab);
    gemm_k<128, 128, 256, true, true, true, false>
        <<<dim3(NNP / 128, 2), 256, 0, stream>>>(Ab, Bb, W2T, b_rel2, Cb, nullptr);

    // L3: y = h2@w_rel3 -> Ab, r = h2@w_root3 -> Bb (one dispatch)
    gemm_k<128, 256, 256, false, false, false, true>
        <<<dim3(NNP / 128, 2), 256, 0, stream>>>(Cb, nullptr, W3T, nullptr, Ab, Bb);

    // fused gather+elu per node (aggb structure), then segmented graph-mean
    aggf_k<<<NN / 4, 256, 0, stream>>>(Ab, Bb, b_rel3, rowptr, colsrc, Cb);
    sum_k<<<NN / 25, 128, 0, stream>>>(Cb, batch, outp);
    divide_k<<<(NG * 128 + 255) / 256, 256, 0, stream>>>(bounds, outp);
}